// Round 4
// baseline (1188.833 us; speedup 1.0000x reference)
//
#include <hip/hip_runtime.h>

#define BN_EPS 1e-5f

// ---------- degree count (int) ----------
__global__ void k_zero_i(int* __restrict__ p, int n) {
    int i = blockIdx.x * blockDim.x + threadIdx.x;
    if (i < n) p[i] = 0;
}

__global__ void k_count(const int* __restrict__ dst, int* __restrict__ cnt, int E) {
    int e = blockIdx.x * blockDim.x + threadIdx.x;
    if (e < E) atomicAdd(&cnt[dst[e]], 1);
}

__global__ void k_dinv(const int* __restrict__ cnt, float* __restrict__ dinv, int n) {
    int i = blockIdx.x * blockDim.x + threadIdx.x;
    if (i < n) dinv[i] = rsqrtf((float)(cnt[i] + 1));   // +1 self loop
}

// ---------- exclusive scan (two-level) ----------
__global__ void k_scan1(const int* __restrict__ cnt, int* __restrict__ rs,
                        int* __restrict__ bsum, int n) {
    __shared__ int sh[1024];
    const int t = threadIdx.x;
    const int gid = blockIdx.x * 1024 + t;
    int v = (gid < n) ? cnt[gid] : 0;
    sh[t] = v;
    __syncthreads();
    for (int off = 1; off < 1024; off <<= 1) {
        int u = (t >= off) ? sh[t - off] : 0;
        __syncthreads();
        sh[t] += u;
        __syncthreads();
    }
    if (gid < n) rs[gid] = sh[t] - v;       // exclusive
    if (t == 1023) bsum[blockIdx.x] = sh[1023];
}

__global__ void k_scan2(int* __restrict__ bsum, int nb) {
    __shared__ int sh[1024];
    const int t = threadIdx.x;
    int v = (t < nb) ? bsum[t] : 0;
    sh[t] = v;
    __syncthreads();
    for (int off = 1; off < 1024; off <<= 1) {
        int u = (t >= off) ? sh[t - off] : 0;
        __syncthreads();
        sh[t] += u;
        __syncthreads();
    }
    if (t < nb) bsum[t] = sh[t] - v;        // exclusive
}

__global__ void k_scan3(int* __restrict__ rs, int* __restrict__ cur,
                        const int* __restrict__ bsum, int n) {
    int i = blockIdx.x * blockDim.x + threadIdx.x;
    if (i < n) {
        int v = rs[i] + bsum[i >> 10];
        rs[i] = v;
        cur[i] = v;
    }
}

// ---------- CSR fill ----------
__global__ void k_fill(const int* __restrict__ src, const int* __restrict__ dst,
                       int* __restrict__ cur, int* __restrict__ csrc, int E) {
    int e = blockIdx.x * blockDim.x + threadIdx.x;
    if (e < E) {
        int pos = atomicAdd(&cur[dst[e]], 1);
        csrc[pos] = src[e];
    }
}

// ---------- layer-1 pre-aggregation: XA[d] = dinv[d]*(x[d]*dinv[d] + sum x[s]*dinv[s]) ----------
// 256 threads = 32 groups of 8 lanes; lanes 0..5 each own 4 of 24 features.
__global__ void k_agg24(const float* __restrict__ x, const int* __restrict__ rs,
                        const int* __restrict__ rend, const int* __restrict__ csrc,
                        const float* __restrict__ dinv, float* __restrict__ XA, int n) {
    const int g = threadIdx.x >> 3;
    const int j = threadIdx.x & 7;
    const bool act = (j < 6);
    for (int d = blockIdx.x * 32 + g; d < n; d += gridDim.x * 32) {
        const float di = dinv[d];
        const int beg = rs[d], end = rend[d];
        float4 acc = make_float4(0.f, 0.f, 0.f, 0.f);
        if (act) {
            float4 v = *(const float4*)&x[(size_t)d * 24 + j * 4];
            acc.x = v.x * di; acc.y = v.y * di; acc.z = v.z * di; acc.w = v.w * di;
        }
        int e = beg;
        for (; e + 1 < end; e += 2) {
            int s0 = csrc[e], s1 = csrc[e + 1];
            float w0 = dinv[s0], w1 = dinv[s1];
            if (act) {
                float4 v0 = *(const float4*)&x[(size_t)s0 * 24 + j * 4];
                float4 v1 = *(const float4*)&x[(size_t)s1 * 24 + j * 4];
                acc.x = fmaf(v0.x, w0, acc.x); acc.y = fmaf(v0.y, w0, acc.y);
                acc.z = fmaf(v0.z, w0, acc.z); acc.w = fmaf(v0.w, w0, acc.w);
                acc.x = fmaf(v1.x, w1, acc.x); acc.y = fmaf(v1.y, w1, acc.y);
                acc.z = fmaf(v1.z, w1, acc.z); acc.w = fmaf(v1.w, w1, acc.w);
            }
        }
        if (e < end) {
            int s = csrc[e];
            float w = dinv[s];
            if (act) {
                float4 v = *(const float4*)&x[(size_t)s * 24 + j * 4];
                acc.x = fmaf(v.x, w, acc.x); acc.y = fmaf(v.y, w, acc.y);
                acc.z = fmaf(v.z, w, acc.z); acc.w = fmaf(v.w, w, acc.w);
            }
        }
        if (act) {
            acc.x *= di; acc.y *= di; acc.z *= di; acc.w *= di;
            *(float4*)&XA[(size_t)d * 24 + j * 4] = acc;
        }
    }
}

// ---------- GEMM: out = (X*aff_a + aff_c) @ W ----------
// EPI=true : out = relu(acc + b) row-major + column stats (layer 1)
// EPI=false: out = acc, chunk-major [chunk][n][16] (feeds chunked aggregation)
template<int K, int F, int RT, bool AFF, bool EPI>
__global__ __launch_bounds__(256) void k_gemm2(const float* __restrict__ X,
        const float* __restrict__ W, const float* __restrict__ aff,
        float* __restrict__ O, const float* __restrict__ b,
        float* __restrict__ sums, int n) {
    constexpr int COLG = F / 4;
    constexpr int ROWG = 256 / COLG;
    constexpr int TR = ROWG * RT;
    __shared__ float sW[K * F];
    __shared__ float sX[TR * K];
    __shared__ float sRed[2 * F];
    const int tid = threadIdx.x;
    const int tx = tid % COLG;
    const int ty = tid / COLG;

    for (int i = tid * 4; i < K * F; i += 1024)
        *(float4*)&sW[i] = *(const float4*)&W[i];

    float4 bv;
    float ls[4], lq[4];
    if constexpr (EPI) {
        bv = *(const float4*)&b[tx * 4];
        #pragma unroll
        for (int c = 0; c < 4; ++c) { ls[c] = 0.f; lq[c] = 0.f; }
    }

    const int ntiles = (n + TR - 1) / TR;
    for (int tile = blockIdx.x; tile < ntiles; tile += gridDim.x) {
        const int r0 = tile * TR;
        __syncthreads();
        for (int i = tid * 4; i < TR * K; i += 1024) {
            const int row = i / K;
            const int kk = i % K;
            float4 v;
            if (r0 + row < n) {
                v = *(const float4*)&X[(size_t)(r0 + row) * K + kk];
                if constexpr (AFF) {
                    v.x = fmaf(v.x, aff[kk],     aff[K + kk]);
                    v.y = fmaf(v.y, aff[kk + 1], aff[K + kk + 1]);
                    v.z = fmaf(v.z, aff[kk + 2], aff[K + kk + 2]);
                    v.w = fmaf(v.w, aff[kk + 3], aff[K + kk + 3]);
                }
            } else {
                v = make_float4(0.f, 0.f, 0.f, 0.f);
            }
            *(float4*)&sX[i] = v;
        }
        __syncthreads();

        float acc[RT][4];
        #pragma unroll
        for (int r = 0; r < RT; ++r)
            #pragma unroll
            for (int c = 0; c < 4; ++c) acc[r][c] = 0.0f;

        for (int k4 = 0; k4 < K; k4 += 4) {
            float xk[RT][4];
            #pragma unroll
            for (int r = 0; r < RT; ++r) {
                float4 t = *(const float4*)&sX[(ty * RT + r) * K + k4];
                xk[r][0] = t.x; xk[r][1] = t.y; xk[r][2] = t.z; xk[r][3] = t.w;
            }
            float4 wv[4];
            #pragma unroll
            for (int kk = 0; kk < 4; ++kk)
                wv[kk] = *(const float4*)&sW[(k4 + kk) * F + tx * 4];
            #pragma unroll
            for (int kk = 0; kk < 4; ++kk)
                #pragma unroll
                for (int r = 0; r < RT; ++r) {
                    const float xr = xk[r][kk];
                    acc[r][0] = fmaf(xr, wv[kk].x, acc[r][0]);
                    acc[r][1] = fmaf(xr, wv[kk].y, acc[r][1]);
                    acc[r][2] = fmaf(xr, wv[kk].z, acc[r][2]);
                    acc[r][3] = fmaf(xr, wv[kk].w, acc[r][3]);
                }
        }

        #pragma unroll
        for (int r = 0; r < RT; ++r) {
            const int row = r0 + ty * RT + r;
            if (row < n) {
                if constexpr (EPI) {
                    float4 o;
                    o.x = fmaxf(acc[r][0] + bv.x, 0.f);
                    o.y = fmaxf(acc[r][1] + bv.y, 0.f);
                    o.z = fmaxf(acc[r][2] + bv.z, 0.f);
                    o.w = fmaxf(acc[r][3] + bv.w, 0.f);
                    ls[0] += o.x; lq[0] += o.x * o.x;
                    ls[1] += o.y; lq[1] += o.y * o.y;
                    ls[2] += o.z; lq[2] += o.z * o.z;
                    ls[3] += o.w; lq[3] += o.w * o.w;
                    *(float4*)&O[(size_t)row * F + tx * 4] = o;
                } else {
                    const int col = tx * 4;
                    const int chunk = col >> 4;
                    const int off = col & 15;
                    *(float4*)&O[((size_t)chunk * n + row) * 16 + off] =
                        make_float4(acc[r][0], acc[r][1], acc[r][2], acc[r][3]);
                }
            }
        }
    }

    if constexpr (EPI) {
        __syncthreads();
        if (tid < 2 * F) sRed[tid] = 0.f;
        __syncthreads();
        #pragma unroll
        for (int c = 0; c < 4; ++c) {
            atomicAdd(&sRed[tx * 4 + c], ls[c]);
            atomicAdd(&sRed[F + tx * 4 + c], lq[c]);
        }
        __syncthreads();
        if (tid < F) {
            atomicAdd(&sums[tid], sRed[tid]);
            atomicAdd(&sums[F + tid], sRed[F + tid]);
        }
    }
}

// ---------- chunked CSR aggregation (+bias+ReLU+stats), 16 features/pass ----------
// Hc chunk-major [F/16][n][16]; A row-major [n][F]. One launch per chunk.
template<int F>
__global__ void k_aggc(const float* __restrict__ Hc, const int* __restrict__ rs,
                       const int* __restrict__ rend, const int* __restrict__ csrc,
                       const float* __restrict__ dinv, const float* __restrict__ b,
                       float* __restrict__ A, float* __restrict__ sums,
                       int n, int chunk) {
    const float* __restrict__ Hp = Hc + (size_t)chunk * n * 16;
    const int g = threadIdx.x >> 4;     // 16 node-groups per block
    const int f = threadIdx.x & 15;
    const int col = chunk * 16 + f;
    const float bf = b[col];
    float ls = 0.f, lq = 0.f;
    for (int d = blockIdx.x * 16 + g; d < n; d += gridDim.x * 16) {
        const int beg = rs[d], end = rend[d];
        const float di = dinv[d];
        float acc = Hp[(size_t)d * 16 + f] * di;   // self loop (x di again below)
        int j = beg;
        for (; j + 1 < end; j += 2) {
            int s0 = csrc[j], s1 = csrc[j + 1];
            float w0 = dinv[s0], w1 = dinv[s1];
            float h0 = Hp[(size_t)s0 * 16 + f], h1 = Hp[(size_t)s1 * 16 + f];
            acc = fmaf(h0, w0, acc);
            acc = fmaf(h1, w1, acc);
        }
        if (j < end) {
            int s = csrc[j];
            acc = fmaf(Hp[(size_t)s * 16 + f], dinv[s], acc);
        }
        float v = fmaxf(fmaf(acc, di, bf), 0.0f);
        A[(size_t)d * F + col] = v;
        ls += v;
        lq += v * v;
    }
    __shared__ float sR[2][256];
    sR[0][threadIdx.x] = ls;
    sR[1][threadIdx.x] = lq;
    __syncthreads();
    if (threadIdx.x < 16) {
        float a = 0.f, q = 0.f;
        for (int k = 0; k < 16; ++k) { a += sR[0][k * 16 + threadIdx.x]; q += sR[1][k * 16 + threadIdx.x]; }
        const int c2 = chunk * 16 + threadIdx.x;
        atomicAdd(&sums[c2], a);
        atomicAdd(&sums[F + c2], q);
    }
}

// ---------- BN fold ----------
__global__ void k_bnprep(const float* __restrict__ sums, const float* __restrict__ g,
                         const float* __restrict__ be, float* __restrict__ aff,
                         int F, float invn) {
    int f = threadIdx.x;
    if (f < F) {
        float mean = sums[f] * invn;
        float var = sums[F + f] * invn - mean * mean;
        float a = rsqrtf(var + BN_EPS) * g[f];
        aff[f] = a;
        aff[F + f] = be[f] - mean * a;
    }
}

// ---------- final 64->2 GEMM with input affine ----------
__global__ void k_gemm4(const float* __restrict__ X, const float* __restrict__ W,
                        const float* __restrict__ aff, float* __restrict__ H, int n) {
    int i = blockIdx.x * blockDim.x + threadIdx.x;
    if (i >= n) return;
    float a0 = 0.0f, a1 = 0.0f;
    #pragma unroll 8
    for (int k = 0; k < 64; ++k) {
        float v = X[i * 64 + k] * aff[k] + aff[64 + k];
        a0 = fmaf(v, W[2 * k], a0);
        a1 = fmaf(v, W[2 * k + 1], a1);
    }
    H[2 * i] = a0;
    H[2 * i + 1] = a1;
}

// ---------- final aggregation (F=2) + bias + log_softmax ----------
__global__ void k_last(const float* __restrict__ H, const int* __restrict__ rs,
                       const int* __restrict__ rend, const int* __restrict__ csrc,
                       const float* __restrict__ dinv, const float* __restrict__ b,
                       float* __restrict__ out, int n) {
    int d = blockIdx.x * blockDim.x + threadIdx.x;
    if (d >= n) return;
    const float di = dinv[d];
    float a0 = H[2 * d] * di, a1 = H[2 * d + 1] * di;
    const int beg = rs[d], end = rend[d];
    for (int j = beg; j < end; ++j) {
        int s = csrc[j];
        float w = dinv[s];
        a0 = fmaf(H[2 * s], w, a0);
        a1 = fmaf(H[2 * s + 1], w, a1);
    }
    float v0 = fmaf(a0, di, b[0]);
    float v1 = fmaf(a1, di, b[1]);
    float m = fmaxf(v0, v1);
    float l = logf(expf(v0 - m) + expf(v1 - m)) + m;
    out[2 * d] = v0 - l;
    out[2 * d + 1] = v1 - l;
}

extern "C" void kernel_launch(void* const* d_in, const int* in_sizes, int n_in,
                              void* d_out, int out_size, void* d_ws, size_t ws_size,
                              hipStream_t stream) {
    const float* x   = (const float*)d_in[0];
    const int*   ei  = (const int*)d_in[1];
    const float* W1  = (const float*)d_in[2];
    const float* b1  = (const float*)d_in[3];
    const float* g1  = (const float*)d_in[4];
    const float* be1 = (const float*)d_in[5];
    const float* W2  = (const float*)d_in[6];
    const float* b2  = (const float*)d_in[7];
    const float* g2  = (const float*)d_in[8];
    const float* be2 = (const float*)d_in[9];
    const float* W3  = (const float*)d_in[10];
    const float* b3  = (const float*)d_in[11];
    const float* g3  = (const float*)d_in[12];
    const float* be3 = (const float*)d_in[13];
    const float* W4  = (const float*)d_in[14];
    const float* b4  = (const float*)d_in[15];
    float* out = (float*)d_out;

    const int N = in_sizes[0] / 24;
    const int E = in_sizes[1] / 2;
    const int* srcI = ei;
    const int* dstI = ei + E;

    // ---- workspace carve ----
    int* cnt   = (int*)d_ws;                 // N
    int* rs    = cnt + N;                    // N
    int* cur   = rs + N;                     // N
    int* csrc  = cur + N;                    // E
    int* bsum  = csrc + E;                   // 1024
    float* dinv = (float*)(bsum + 1024);     // N
    float* H    = dinv + N;                  // N*128 (XA for layer1 / chunk-major H)
    float* A    = H + (size_t)N * 128;       // N*128
    float* S    = A + (size_t)N * 128;       // 1280 stats
    float* sums1 = S,        *aff1 = S + 256;
    float* sums2 = S + 512,  *aff2 = S + 768;
    float* sums3 = S + 1024, *aff3 = S + 1152;

    hipMemsetAsync(S, 0, 1280 * sizeof(float), stream);

    const int TB = 256;
    const int nb = (N + 1023) / 1024;

    // ---- CSR build + dinv ----
    k_zero_i<<<(N + TB - 1) / TB, TB, 0, stream>>>(cnt, N);
    k_count<<<(E + TB - 1) / TB, TB, 0, stream>>>(dstI, cnt, E);
    k_dinv<<<(N + TB - 1) / TB, TB, 0, stream>>>(cnt, dinv, N);
    k_scan1<<<nb, 1024, 0, stream>>>(cnt, rs, bsum, N);
    k_scan2<<<1, 1024, 0, stream>>>(bsum, nb);
    k_scan3<<<(N + TB - 1) / TB, TB, 0, stream>>>(rs, cur, bsum, N);
    k_fill<<<(E + TB - 1) / TB, TB, 0, stream>>>(srcI, dstI, cur, csrc, E);
    // after k_fill, cur[d] == row end

    // ----- layer 1: pre-aggregate x (24-wide), GEMM 24->128 + bias/relu/stats -----
    k_agg24<<<2048, 256, 0, stream>>>(x, rs, cur, csrc, dinv, H, N);
    k_gemm2<24, 128, 4, false, true><<<1024, 256, 0, stream>>>(H, W1, nullptr, A, b1, sums1, N);
    k_bnprep<<<1, 128, 0, stream>>>(sums1, g1, be1, aff1, 128, 1.0f / (float)N);

    // ----- layer 2: GEMM 128->128 (chunk-major H), chunked agg -----
    k_gemm2<128, 128, 4, true, false><<<1024, 256, 0, stream>>>(A, W2, aff1, H, nullptr, nullptr, N);
    for (int c = 0; c < 8; ++c)
        k_aggc<128><<<2048, 256, 0, stream>>>(H, rs, cur, csrc, dinv, b2, A, sums2, N, c);
    k_bnprep<<<1, 128, 0, stream>>>(sums2, g2, be2, aff2, 128, 1.0f / (float)N);

    // ----- layer 3: GEMM 128->64 (chunk-major H), chunked agg -----
    k_gemm2<128, 64, 2, true, false><<<1024, 256, 0, stream>>>(A, W3, aff2, H, nullptr, nullptr, N);
    for (int c = 0; c < 4; ++c)
        k_aggc<64><<<2048, 256, 0, stream>>>(H, rs, cur, csrc, dinv, b3, A, sums3, N, c);
    k_bnprep<<<1, 64, 0, stream>>>(sums3, g3, be3, aff3, 64, 1.0f / (float)N);

    // ----- layer 4: 64 -> 2, log_softmax -----
    k_gemm4<<<(N + TB - 1) / TB, TB, 0, stream>>>(A, W4, aff3, H, N);
    k_last<<<(N + TB - 1) / TB, TB, 0, stream>>>(H, rs, cur, csrc, dinv, b4, out, N);
}

// Round 5
// 1074.624 us; speedup vs baseline: 1.1063x; 1.1063x over previous
//
#include <hip/hip_runtime.h>
#include <hip/hip_fp16.h>

#define BN_EPS 1e-5f

// ---------- degree count (int) ----------
__global__ void k_zero_i(int* __restrict__ p, int n) {
    int i = blockIdx.x * blockDim.x + threadIdx.x;
    if (i < n) p[i] = 0;
}

__global__ void k_count(const int* __restrict__ dst, int* __restrict__ cnt, int E) {
    int e = blockIdx.x * blockDim.x + threadIdx.x;
    if (e < E) atomicAdd(&cnt[dst[e]], 1);
}

__global__ void k_dinv(const int* __restrict__ cnt, float* __restrict__ dinv, int n) {
    int i = blockIdx.x * blockDim.x + threadIdx.x;
    if (i < n) dinv[i] = rsqrtf((float)(cnt[i] + 1));   // +1 self loop
}

// ---------- exclusive scan (two-level) ----------
__global__ void k_scan1(const int* __restrict__ cnt, int* __restrict__ rs,
                        int* __restrict__ bsum, int n) {
    __shared__ int sh[1024];
    const int t = threadIdx.x;
    const int gid = blockIdx.x * 1024 + t;
    int v = (gid < n) ? cnt[gid] : 0;
    sh[t] = v;
    __syncthreads();
    for (int off = 1; off < 1024; off <<= 1) {
        int u = (t >= off) ? sh[t - off] : 0;
        __syncthreads();
        sh[t] += u;
        __syncthreads();
    }
    if (gid < n) rs[gid] = sh[t] - v;       // exclusive
    if (t == 1023) bsum[blockIdx.x] = sh[1023];
}

__global__ void k_scan2(int* __restrict__ bsum, int nb) {
    __shared__ int sh[1024];
    const int t = threadIdx.x;
    int v = (t < nb) ? bsum[t] : 0;
    sh[t] = v;
    __syncthreads();
    for (int off = 1; off < 1024; off <<= 1) {
        int u = (t >= off) ? sh[t - off] : 0;
        __syncthreads();
        sh[t] += u;
        __syncthreads();
    }
    if (t < nb) bsum[t] = sh[t] - v;        // exclusive
}

__global__ void k_scan3(int* __restrict__ rs, int* __restrict__ cur,
                        const int* __restrict__ bsum, int n) {
    int i = blockIdx.x * blockDim.x + threadIdx.x;
    if (i < n) {
        int v = rs[i] + bsum[i >> 10];
        rs[i] = v;
        cur[i] = v;
    }
}

// ---------- bucketed CSR fill ----------
// bucket b = dst >> 7 (128 nodes per bucket). bcnt from cnt, scan, then
// pass1 groups (dst,src) pairs by bucket; pass2 places within-bucket
// (consecutive threads -> same bucket -> csrc line written by one WG).
__global__ void k_bcnt(const int* __restrict__ cnt, int* __restrict__ bcnt,
                       int n, int nb) {
    int b = blockIdx.x * blockDim.x + threadIdx.x;
    if (b >= nb) return;
    int s = 0;
    int base = b << 7;
    for (int k = 0; k < 128; ++k) {
        int id = base + k;
        if (id < n) s += cnt[id];
    }
    bcnt[b] = s;
}

__global__ void k_bscan(const int* __restrict__ bcnt, int* __restrict__ bcur, int nb) {
    __shared__ int sh[1024];
    const int t = threadIdx.x;
    int v = (t < nb) ? bcnt[t] : 0;
    sh[t] = v;
    __syncthreads();
    for (int off = 1; off < 1024; off <<= 1) {
        int u = (t >= off) ? sh[t - off] : 0;
        __syncthreads();
        sh[t] += u;
        __syncthreads();
    }
    if (t < nb) bcur[t] = sh[t] - v;        // exclusive
}

__global__ void k_pass1(const int* __restrict__ src, const int* __restrict__ dst,
                        int* __restrict__ bcur, int2* __restrict__ pairs, int E) {
    int e = blockIdx.x * blockDim.x + threadIdx.x;
    if (e < E) {
        int d = dst[e];
        int pos = atomicAdd(&bcur[d >> 7], 1);
        pairs[pos] = make_int2(d, src[e]);
    }
}

__global__ void k_pass2(const int2* __restrict__ pairs, int* __restrict__ cur,
                        int* __restrict__ csrc, int E) {
    int e = blockIdx.x * blockDim.x + threadIdx.x;
    if (e < E) {
        int2 p = pairs[e];
        int pos = atomicAdd(&cur[p.x], 1);
        csrc[pos] = p.y;
    }
}

// ---------- layer-1 pre-aggregation on raw x (24-wide) ----------
__global__ void k_agg24(const float* __restrict__ x, const int* __restrict__ rs,
                        const int* __restrict__ rend, const int* __restrict__ csrc,
                        const float* __restrict__ dinv, float* __restrict__ XA, int n) {
    const int g = threadIdx.x >> 3;
    const int j = threadIdx.x & 7;
    const bool act = (j < 6);
    for (int d = blockIdx.x * 32 + g; d < n; d += gridDim.x * 32) {
        const float di = dinv[d];
        const int beg = rs[d], end = rend[d];
        float4 acc = make_float4(0.f, 0.f, 0.f, 0.f);
        if (act) {
            float4 v = *(const float4*)&x[(size_t)d * 24 + j * 4];
            acc.x = v.x * di; acc.y = v.y * di; acc.z = v.z * di; acc.w = v.w * di;
        }
        int e = beg;
        for (; e + 1 < end; e += 2) {
            int s0 = csrc[e], s1 = csrc[e + 1];
            float w0 = dinv[s0], w1 = dinv[s1];
            if (act) {
                float4 v0 = *(const float4*)&x[(size_t)s0 * 24 + j * 4];
                float4 v1 = *(const float4*)&x[(size_t)s1 * 24 + j * 4];
                acc.x = fmaf(v0.x, w0, acc.x); acc.y = fmaf(v0.y, w0, acc.y);
                acc.z = fmaf(v0.z, w0, acc.z); acc.w = fmaf(v0.w, w0, acc.w);
                acc.x = fmaf(v1.x, w1, acc.x); acc.y = fmaf(v1.y, w1, acc.y);
                acc.z = fmaf(v1.z, w1, acc.z); acc.w = fmaf(v1.w, w1, acc.w);
            }
        }
        if (e < end) {
            int s = csrc[e];
            float w = dinv[s];
            if (act) {
                float4 v = *(const float4*)&x[(size_t)s * 24 + j * 4];
                acc.x = fmaf(v.x, w, acc.x); acc.y = fmaf(v.y, w, acc.y);
                acc.z = fmaf(v.z, w, acc.z); acc.w = fmaf(v.w, w, acc.w);
            }
        }
        if (act) {
            acc.x *= di; acc.y *= di; acc.z *= di; acc.w *= di;
            *(float4*)&XA[(size_t)d * 24 + j * 4] = acc;
        }
    }
}

// ---------- GEMM: out = (X*aff_a + aff_c) @ W ----------
// EPI=true : O=float*, out = relu(acc + b) + column stats (layer 1)
// EPI=false: O=__half* row-major (feeds fp16 gather aggregation)
template<int K, int F, int RT, bool AFF, bool EPI>
__global__ __launch_bounds__(256) void k_gemm2(const float* __restrict__ X,
        const float* __restrict__ W, const float* __restrict__ aff,
        void* __restrict__ Ov, const float* __restrict__ b,
        float* __restrict__ sums, int n) {
    constexpr int COLG = F / 4;
    constexpr int ROWG = 256 / COLG;
    constexpr int TR = ROWG * RT;
    __shared__ float sW[K * F];
    __shared__ float sX[TR * K];
    __shared__ float sRed[2 * F];
    const int tid = threadIdx.x;
    const int tx = tid % COLG;
    const int ty = tid / COLG;

    for (int i = tid * 4; i < K * F; i += 1024)
        *(float4*)&sW[i] = *(const float4*)&W[i];

    float4 bv;
    float ls[4], lq[4];
    if constexpr (EPI) {
        bv = *(const float4*)&b[tx * 4];
        #pragma unroll
        for (int c = 0; c < 4; ++c) { ls[c] = 0.f; lq[c] = 0.f; }
    }

    const int ntiles = (n + TR - 1) / TR;
    for (int tile = blockIdx.x; tile < ntiles; tile += gridDim.x) {
        const int r0 = tile * TR;
        __syncthreads();
        for (int i = tid * 4; i < TR * K; i += 1024) {
            const int row = i / K;
            const int kk = i % K;
            float4 v;
            if (r0 + row < n) {
                v = *(const float4*)&X[(size_t)(r0 + row) * K + kk];
                if constexpr (AFF) {
                    v.x = fmaf(v.x, aff[kk],     aff[K + kk]);
                    v.y = fmaf(v.y, aff[kk + 1], aff[K + kk + 1]);
                    v.z = fmaf(v.z, aff[kk + 2], aff[K + kk + 2]);
                    v.w = fmaf(v.w, aff[kk + 3], aff[K + kk + 3]);
                }
            } else {
                v = make_float4(0.f, 0.f, 0.f, 0.f);
            }
            *(float4*)&sX[i] = v;
        }
        __syncthreads();

        float acc[RT][4];
        #pragma unroll
        for (int r = 0; r < RT; ++r)
            #pragma unroll
            for (int c = 0; c < 4; ++c) acc[r][c] = 0.0f;

        for (int k4 = 0; k4 < K; k4 += 4) {
            float xk[RT][4];
            #pragma unroll
            for (int r = 0; r < RT; ++r) {
                float4 t = *(const float4*)&sX[(ty * RT + r) * K + k4];
                xk[r][0] = t.x; xk[r][1] = t.y; xk[r][2] = t.z; xk[r][3] = t.w;
            }
            float4 wv[4];
            #pragma unroll
            for (int kk = 0; kk < 4; ++kk)
                wv[kk] = *(const float4*)&sW[(k4 + kk) * F + tx * 4];
            #pragma unroll
            for (int kk = 0; kk < 4; ++kk)
                #pragma unroll
                for (int r = 0; r < RT; ++r) {
                    const float xr = xk[r][kk];
                    acc[r][0] = fmaf(xr, wv[kk].x, acc[r][0]);
                    acc[r][1] = fmaf(xr, wv[kk].y, acc[r][1]);
                    acc[r][2] = fmaf(xr, wv[kk].z, acc[r][2]);
                    acc[r][3] = fmaf(xr, wv[kk].w, acc[r][3]);
                }
        }

        #pragma unroll
        for (int r = 0; r < RT; ++r) {
            const int row = r0 + ty * RT + r;
            if (row < n) {
                if constexpr (EPI) {
                    float4 o;
                    o.x = fmaxf(acc[r][0] + bv.x, 0.f);
                    o.y = fmaxf(acc[r][1] + bv.y, 0.f);
                    o.z = fmaxf(acc[r][2] + bv.z, 0.f);
                    o.w = fmaxf(acc[r][3] + bv.w, 0.f);
                    ls[0] += o.x; lq[0] += o.x * o.x;
                    ls[1] += o.y; lq[1] += o.y * o.y;
                    ls[2] += o.z; lq[2] += o.z * o.z;
                    ls[3] += o.w; lq[3] += o.w * o.w;
                    *(float4*)&((float*)Ov)[(size_t)row * F + tx * 4] = o;
                } else {
                    union { float2 f2; __half2 h2[2]; } u;
                    u.h2[0] = __floats2half2_rn(acc[r][0], acc[r][1]);
                    u.h2[1] = __floats2half2_rn(acc[r][2], acc[r][3]);
                    *(float2*)&((__half*)Ov)[(size_t)row * F + tx * 4] = u.f2;
                }
            }
        }
    }

    if constexpr (EPI) {
        __syncthreads();
        if (tid < 2 * F) sRed[tid] = 0.f;
        __syncthreads();
        #pragma unroll
        for (int c = 0; c < 4; ++c) {
            atomicAdd(&sRed[tx * 4 + c], ls[c]);
            atomicAdd(&sRed[F + tx * 4 + c], lq[c]);
        }
        __syncthreads();
        if (tid < F) {
            atomicAdd(&sums[tid], sRed[tid]);
            atomicAdd(&sums[F + tid], sRed[F + tid]);
        }
    }
}

// ---------- CSR gather aggregation (fp16 H), fused self-loop+bias+ReLU+stats ----------
template<int F>
__global__ void k_aggf(const __half* __restrict__ Hh, const int* __restrict__ rs,
                       const int* __restrict__ rend, const int* __restrict__ csrc,
                       const float* __restrict__ dinv, const float* __restrict__ b,
                       float* __restrict__ A, float* __restrict__ sums, int n) {
    const int f = threadIdx.x;
    const float bf = b[f];
    float ls = 0.0f, lq = 0.0f;
    for (int d = blockIdx.x; d < n; d += gridDim.x) {
        const int beg = rs[d];
        const int end = rend[d];
        const float di = dinv[d];
        float acc = __half2float(Hh[(size_t)d * F + f]) * di;  // self loop
        int j = beg;
        for (; j + 3 < end; j += 4) {
            int s0 = csrc[j], s1 = csrc[j + 1], s2 = csrc[j + 2], s3 = csrc[j + 3];
            float w0 = dinv[s0], w1 = dinv[s1], w2 = dinv[s2], w3 = dinv[s3];
            float h0 = __half2float(Hh[(size_t)s0 * F + f]);
            float h1 = __half2float(Hh[(size_t)s1 * F + f]);
            float h2 = __half2float(Hh[(size_t)s2 * F + f]);
            float h3 = __half2float(Hh[(size_t)s3 * F + f]);
            acc = fmaf(h0, w0, acc);
            acc = fmaf(h1, w1, acc);
            acc = fmaf(h2, w2, acc);
            acc = fmaf(h3, w3, acc);
        }
        for (; j < end; ++j) {
            int s = csrc[j];
            acc = fmaf(__half2float(Hh[(size_t)s * F + f]), dinv[s], acc);
        }
        float v = fmaxf(fmaf(acc, di, bf), 0.0f);
        A[(size_t)d * F + f] = v;
        ls += v;
        lq += v * v;
    }
    atomicAdd(&sums[f], ls);
    atomicAdd(&sums[F + f], lq);
}

// ---------- BN fold ----------
__global__ void k_bnprep(const float* __restrict__ sums, const float* __restrict__ g,
                         const float* __restrict__ be, float* __restrict__ aff,
                         int F, float invn) {
    int f = threadIdx.x;
    if (f < F) {
        float mean = sums[f] * invn;
        float var = sums[F + f] * invn - mean * mean;
        float a = rsqrtf(var + BN_EPS) * g[f];
        aff[f] = a;
        aff[F + f] = be[f] - mean * a;
    }
}

// ---------- final 64->2 GEMM with input affine ----------
__global__ void k_gemm4(const float* __restrict__ X, const float* __restrict__ W,
                        const float* __restrict__ aff, float* __restrict__ H, int n) {
    int i = blockIdx.x * blockDim.x + threadIdx.x;
    if (i >= n) return;
    float a0 = 0.0f, a1 = 0.0f;
    #pragma unroll 8
    for (int k = 0; k < 64; ++k) {
        float v = X[i * 64 + k] * aff[k] + aff[64 + k];
        a0 = fmaf(v, W[2 * k], a0);
        a1 = fmaf(v, W[2 * k + 1], a1);
    }
    H[2 * i] = a0;
    H[2 * i + 1] = a1;
}

// ---------- final aggregation (F=2) + bias + log_softmax ----------
__global__ void k_last(const float* __restrict__ H, const int* __restrict__ rs,
                       const int* __restrict__ rend, const int* __restrict__ csrc,
                       const float* __restrict__ dinv, const float* __restrict__ b,
                       float* __restrict__ out, int n) {
    int d = blockIdx.x * blockDim.x + threadIdx.x;
    if (d >= n) return;
    const float di = dinv[d];
    float a0 = H[2 * d] * di, a1 = H[2 * d + 1] * di;
    const int beg = rs[d], end = rend[d];
    for (int j = beg; j < end; ++j) {
        int s = csrc[j];
        float w = dinv[s];
        a0 = fmaf(H[2 * s], w, a0);
        a1 = fmaf(H[2 * s + 1], w, a1);
    }
    float v0 = fmaf(a0, di, b[0]);
    float v1 = fmaf(a1, di, b[1]);
    float m = fmaxf(v0, v1);
    float l = logf(expf(v0 - m) + expf(v1 - m)) + m;
    out[2 * d] = v0 - l;
    out[2 * d + 1] = v1 - l;
}

extern "C" void kernel_launch(void* const* d_in, const int* in_sizes, int n_in,
                              void* d_out, int out_size, void* d_ws, size_t ws_size,
                              hipStream_t stream) {
    const float* x   = (const float*)d_in[0];
    const int*   ei  = (const int*)d_in[1];
    const float* W1  = (const float*)d_in[2];
    const float* b1  = (const float*)d_in[3];
    const float* g1  = (const float*)d_in[4];
    const float* be1 = (const float*)d_in[5];
    const float* W2  = (const float*)d_in[6];
    const float* b2  = (const float*)d_in[7];
    const float* g2  = (const float*)d_in[8];
    const float* be2 = (const float*)d_in[9];
    const float* W3  = (const float*)d_in[10];
    const float* b3  = (const float*)d_in[11];
    const float* g3  = (const float*)d_in[12];
    const float* be3 = (const float*)d_in[13];
    const float* W4  = (const float*)d_in[14];
    const float* b4  = (const float*)d_in[15];
    float* out = (float*)d_out;

    const int N = in_sizes[0] / 24;
    const int E = in_sizes[1] / 2;
    const int* srcI = ei;
    const int* dstI = ei + E;
    const int NB = (N + 127) >> 7;          // <= 1024 for N <= 131072

    // ---- workspace carve ----
    int* cnt   = (int*)d_ws;                 // N
    int* rs    = cnt + N;                    // N
    int* cur   = rs + N;                     // N
    int* csrc  = cur + N;                    // E
    int* bsum  = csrc + E;                   // 1024
    int* bcnt  = bsum + 1024;                // 1024
    int* bcur  = bcnt + 1024;                // 1024
    float* dinv = (float*)(bcur + 1024);     // N
    float* Hbase = dinv + N;                 // N*128 f32 region (multi-use)
    float* A    = Hbase + (size_t)N * 128;   // N*128 f32
    float* S    = A + (size_t)N * 128;       // 1280 stats
    float* sums1 = S,        *aff1 = S + 256;
    float* sums2 = S + 512,  *aff2 = S + 768;
    float* sums3 = S + 1024, *aff3 = S + 1152;
    // aliases of Hbase (used at disjoint times, stream-ordered):
    int2*   pairs = (int2*)Hbase;            // 2E ints (12.8 MB) during CSR fill
    float*  XA    = Hbase;                   // N*24 f32 for layer-1 pre-agg
    __half* Hh    = (__half*)Hbase;          // N*128 fp16 for layers 2/3
    float*  LG    = Hbase;                   // N*2 logits for layer 4

    hipMemsetAsync(S, 0, 1280 * sizeof(float), stream);

    const int TB = 256;
    const int nb1024 = (N + 1023) / 1024;

    // ---- CSR build + dinv ----
    k_zero_i<<<(N + TB - 1) / TB, TB, 0, stream>>>(cnt, N);
    k_count<<<(E + TB - 1) / TB, TB, 0, stream>>>(dstI, cnt, E);
    k_dinv<<<(N + TB - 1) / TB, TB, 0, stream>>>(cnt, dinv, N);
    k_scan1<<<nb1024, 1024, 0, stream>>>(cnt, rs, bsum, N);
    k_scan2<<<1, 1024, 0, stream>>>(bsum, nb1024);
    k_scan3<<<(N + TB - 1) / TB, TB, 0, stream>>>(rs, cur, bsum, N);
    k_bcnt<<<(NB + TB - 1) / TB, TB, 0, stream>>>(cnt, bcnt, N, NB);
    k_bscan<<<1, 1024, 0, stream>>>(bcnt, bcur, NB);
    k_pass1<<<(E + TB - 1) / TB, TB, 0, stream>>>(srcI, dstI, bcur, pairs, E);
    k_pass2<<<(E + TB - 1) / TB, TB, 0, stream>>>(pairs, cur, csrc, E);
    // after k_pass2, cur[d] == row end

    // ----- layer 1: pre-aggregate x (24-wide), GEMM 24->128 + bias/relu/stats -----
    k_agg24<<<2048, 256, 0, stream>>>(x, rs, cur, csrc, dinv, XA, N);
    k_gemm2<24, 128, 4, false, true><<<1024, 256, 0, stream>>>(XA, W1, nullptr, A, b1, sums1, N);
    k_bnprep<<<1, 128, 0, stream>>>(sums1, g1, be1, aff1, 128, 1.0f / (float)N);

    // ----- layer 2: GEMM 128->128 (fp16 out), fp16 gather agg -----
    k_gemm2<128, 128, 4, true, false><<<1024, 256, 0, stream>>>(A, W2, aff1, Hh, nullptr, nullptr, N);
    k_aggf<128><<<4096, 128, 0, stream>>>(Hh, rs, cur, csrc, dinv, b2, A, sums2, N);
    k_bnprep<<<1, 128, 0, stream>>>(sums2, g2, be2, aff2, 128, 1.0f / (float)N);

    // ----- layer 3: GEMM 128->64 (fp16 out), fp16 gather agg -----
    k_gemm2<128, 64, 2, true, false><<<1024, 256, 0, stream>>>(A, W3, aff2, Hh, nullptr, nullptr, N);
    k_aggf<64><<<4096, 64, 0, stream>>>(Hh, rs, cur, csrc, dinv, b3, A, sums3, N);
    k_bnprep<<<1, 64, 0, stream>>>(sums3, g3, be3, aff3, 64, 1.0f / (float)N);

    // ----- layer 4: 64 -> 2, log_softmax -----
    k_gemm4<<<(N + TB - 1) / TB, TB, 0, stream>>>(A, W4, aff3, LG, N);
    k_last<<<(N + TB - 1) / TB, TB, 0, stream>>>(LG, rs, cur, csrc, dinv, b4, out, N);
}

// Round 6
// 811.732 us; speedup vs baseline: 1.4646x; 1.3239x over previous
//
#include <hip/hip_runtime.h>
#include <hip/hip_fp16.h>

#define BN_EPS 1e-5f

// ---------- degree count (int) ----------
__global__ void k_zero_i(int* __restrict__ p, int n) {
    int i = blockIdx.x * blockDim.x + threadIdx.x;
    if (i < n) p[i] = 0;
}

__global__ void k_count(const int* __restrict__ dst, int* __restrict__ cnt, int E) {
    int e = blockIdx.x * blockDim.x + threadIdx.x;
    if (e < E) atomicAdd(&cnt[dst[e]], 1);
}

__global__ void k_dinv(const int* __restrict__ cnt, float* __restrict__ dinv, int n) {
    int i = blockIdx.x * blockDim.x + threadIdx.x;
    if (i < n) dinv[i] = rsqrtf((float)(cnt[i] + 1));   // +1 self loop
}

// ---------- exclusive scan (two-level) ----------
__global__ void k_scan1(const int* __restrict__ cnt, int* __restrict__ rs,
                        int* __restrict__ bsum, int n) {
    __shared__ int sh[1024];
    const int t = threadIdx.x;
    const int gid = blockIdx.x * 1024 + t;
    int v = (gid < n) ? cnt[gid] : 0;
    sh[t] = v;
    __syncthreads();
    for (int off = 1; off < 1024; off <<= 1) {
        int u = (t >= off) ? sh[t - off] : 0;
        __syncthreads();
        sh[t] += u;
        __syncthreads();
    }
    if (gid < n) rs[gid] = sh[t] - v;       // exclusive
    if (t == 1023) bsum[blockIdx.x] = sh[1023];
}

__global__ void k_scan2(int* __restrict__ bsum, int nb) {
    __shared__ int sh[1024];
    const int t = threadIdx.x;
    int v = (t < nb) ? bsum[t] : 0;
    sh[t] = v;
    __syncthreads();
    for (int off = 1; off < 1024; off <<= 1) {
        int u = (t >= off) ? sh[t - off] : 0;
        __syncthreads();
        sh[t] += u;
        __syncthreads();
    }
    if (t < nb) bsum[t] = sh[t] - v;        // exclusive
}

__global__ void k_scan3(int* __restrict__ rs, int* __restrict__ cur,
                        const int* __restrict__ bsum, int n) {
    int i = blockIdx.x * blockDim.x + threadIdx.x;
    if (i < n) {
        int v = rs[i] + bsum[i >> 10];
        rs[i] = v;
        cur[i] = v;
    }
}

// ---------- bucketed CSR fill, PADDED cursors (1 per 128B line) ----------
// bucket b = dst >> 7 (128 nodes). bcur[b*32] is the cursor — each on its
// own cache line so contended atomics pipeline across L2 channels instead
// of serializing on ~49 shared lines (R5 lesson: 376us -> target ~30us).
__global__ void k_bcnt(const int* __restrict__ cnt, int* __restrict__ bcnt,
                       int n, int nb) {
    int b = blockIdx.x * blockDim.x + threadIdx.x;
    if (b >= nb) return;
    int s = 0;
    int base = b << 7;
    for (int k = 0; k < 128; ++k) {
        int id = base + k;
        if (id < n) s += cnt[id];
    }
    bcnt[b] = s;
}

__global__ void k_bscan(const int* __restrict__ bcnt, int* __restrict__ bcur, int nb) {
    __shared__ int sh[1024];
    const int t = threadIdx.x;
    int v = (t < nb) ? bcnt[t] : 0;
    sh[t] = v;
    __syncthreads();
    for (int off = 1; off < 1024; off <<= 1) {
        int u = (t >= off) ? sh[t - off] : 0;
        __syncthreads();
        sh[t] += u;
        __syncthreads();
    }
    if (t < nb) bcur[t * 32] = sh[t] - v;   // exclusive, padded stride
}

__global__ void k_pass1(const int* __restrict__ src, const int* __restrict__ dst,
                        int* __restrict__ bcur, int2* __restrict__ pairs, int E) {
    int e = blockIdx.x * blockDim.x + threadIdx.x;
    if (e < E) {
        int d = dst[e];
        int pos = atomicAdd(&bcur[(d >> 7) * 32], 1);
        pairs[pos] = make_int2(d, src[e]);
    }
}

__global__ void k_pass2(const int2* __restrict__ pairs, int* __restrict__ cur,
                        int* __restrict__ csrc, int E) {
    int e = blockIdx.x * blockDim.x + threadIdx.x;
    if (e < E) {
        int2 p = pairs[e];
        int pos = atomicAdd(&cur[p.x], 1);
        csrc[pos] = p.y;
    }
}

// ---------- layer-1 pre-aggregation on raw x (24-wide) ----------
__global__ void k_agg24(const float* __restrict__ x, const int* __restrict__ rs,
                        const int* __restrict__ rend, const int* __restrict__ csrc,
                        const float* __restrict__ dinv, float* __restrict__ XA, int n) {
    const int g = threadIdx.x >> 3;
    const int j = threadIdx.x & 7;
    const bool act = (j < 6);
    for (int d = blockIdx.x * 32 + g; d < n; d += gridDim.x * 32) {
        const float di = dinv[d];
        const int beg = rs[d], end = rend[d];
        float4 acc = make_float4(0.f, 0.f, 0.f, 0.f);
        if (act) {
            float4 v = *(const float4*)&x[(size_t)d * 24 + j * 4];
            acc.x = v.x * di; acc.y = v.y * di; acc.z = v.z * di; acc.w = v.w * di;
        }
        int e = beg;
        for (; e + 1 < end; e += 2) {
            int s0 = csrc[e], s1 = csrc[e + 1];
            float w0 = dinv[s0], w1 = dinv[s1];
            if (act) {
                float4 v0 = *(const float4*)&x[(size_t)s0 * 24 + j * 4];
                float4 v1 = *(const float4*)&x[(size_t)s1 * 24 + j * 4];
                acc.x = fmaf(v0.x, w0, acc.x); acc.y = fmaf(v0.y, w0, acc.y);
                acc.z = fmaf(v0.z, w0, acc.z); acc.w = fmaf(v0.w, w0, acc.w);
                acc.x = fmaf(v1.x, w1, acc.x); acc.y = fmaf(v1.y, w1, acc.y);
                acc.z = fmaf(v1.z, w1, acc.z); acc.w = fmaf(v1.w, w1, acc.w);
            }
        }
        if (e < end) {
            int s = csrc[e];
            float w = dinv[s];
            if (act) {
                float4 v = *(const float4*)&x[(size_t)s * 24 + j * 4];
                acc.x = fmaf(v.x, w, acc.x); acc.y = fmaf(v.y, w, acc.y);
                acc.z = fmaf(v.z, w, acc.z); acc.w = fmaf(v.w, w, acc.w);
            }
        }
        if (act) {
            acc.x *= di; acc.y *= di; acc.z *= di; acc.w *= di;
            *(float4*)&XA[(size_t)d * 24 + j * 4] = acc;
        }
    }
}

// ---------- GEMM: out = (X*aff_a + aff_c) @ W ----------
// EPI=true : O=float*, out = relu(acc + b) + column stats (layer 1)
// EPI=false: O=__half* row-major (feeds fp16 gather aggregation)
template<int K, int F, int RT, bool AFF, bool EPI>
__global__ __launch_bounds__(256) void k_gemm2(const float* __restrict__ X,
        const float* __restrict__ W, const float* __restrict__ aff,
        void* __restrict__ Ov, const float* __restrict__ b,
        float* __restrict__ sums, int n) {
    constexpr int COLG = F / 4;
    constexpr int ROWG = 256 / COLG;
    constexpr int TR = ROWG * RT;
    __shared__ float sW[K * F];
    __shared__ float sX[TR * K];
    __shared__ float sRed[2 * F];
    const int tid = threadIdx.x;
    const int tx = tid % COLG;
    const int ty = tid / COLG;

    for (int i = tid * 4; i < K * F; i += 1024)
        *(float4*)&sW[i] = *(const float4*)&W[i];

    float4 bv;
    float ls[4], lq[4];
    if constexpr (EPI) {
        bv = *(const float4*)&b[tx * 4];
        #pragma unroll
        for (int c = 0; c < 4; ++c) { ls[c] = 0.f; lq[c] = 0.f; }
    }

    const int ntiles = (n + TR - 1) / TR;
    for (int tile = blockIdx.x; tile < ntiles; tile += gridDim.x) {
        const int r0 = tile * TR;
        __syncthreads();
        for (int i = tid * 4; i < TR * K; i += 1024) {
            const int row = i / K;
            const int kk = i % K;
            float4 v;
            if (r0 + row < n) {
                v = *(const float4*)&X[(size_t)(r0 + row) * K + kk];
                if constexpr (AFF) {
                    v.x = fmaf(v.x, aff[kk],     aff[K + kk]);
                    v.y = fmaf(v.y, aff[kk + 1], aff[K + kk + 1]);
                    v.z = fmaf(v.z, aff[kk + 2], aff[K + kk + 2]);
                    v.w = fmaf(v.w, aff[kk + 3], aff[K + kk + 3]);
                }
            } else {
                v = make_float4(0.f, 0.f, 0.f, 0.f);
            }
            *(float4*)&sX[i] = v;
        }
        __syncthreads();

        float acc[RT][4];
        #pragma unroll
        for (int r = 0; r < RT; ++r)
            #pragma unroll
            for (int c = 0; c < 4; ++c) acc[r][c] = 0.0f;

        for (int k4 = 0; k4 < K; k4 += 4) {
            float xk[RT][4];
            #pragma unroll
            for (int r = 0; r < RT; ++r) {
                float4 t = *(const float4*)&sX[(ty * RT + r) * K + k4];
                xk[r][0] = t.x; xk[r][1] = t.y; xk[r][2] = t.z; xk[r][3] = t.w;
            }
            float4 wv[4];
            #pragma unroll
            for (int kk = 0; kk < 4; ++kk)
                wv[kk] = *(const float4*)&sW[(k4 + kk) * F + tx * 4];
            #pragma unroll
            for (int kk = 0; kk < 4; ++kk)
                #pragma unroll
                for (int r = 0; r < RT; ++r) {
                    const float xr = xk[r][kk];
                    acc[r][0] = fmaf(xr, wv[kk].x, acc[r][0]);
                    acc[r][1] = fmaf(xr, wv[kk].y, acc[r][1]);
                    acc[r][2] = fmaf(xr, wv[kk].z, acc[r][2]);
                    acc[r][3] = fmaf(xr, wv[kk].w, acc[r][3]);
                }
        }

        #pragma unroll
        for (int r = 0; r < RT; ++r) {
            const int row = r0 + ty * RT + r;
            if (row < n) {
                if constexpr (EPI) {
                    float4 o;
                    o.x = fmaxf(acc[r][0] + bv.x, 0.f);
                    o.y = fmaxf(acc[r][1] + bv.y, 0.f);
                    o.z = fmaxf(acc[r][2] + bv.z, 0.f);
                    o.w = fmaxf(acc[r][3] + bv.w, 0.f);
                    ls[0] += o.x; lq[0] += o.x * o.x;
                    ls[1] += o.y; lq[1] += o.y * o.y;
                    ls[2] += o.z; lq[2] += o.z * o.z;
                    ls[3] += o.w; lq[3] += o.w * o.w;
                    *(float4*)&((float*)Ov)[(size_t)row * F + tx * 4] = o;
                } else {
                    union { float2 f2; __half2 h2[2]; } u;
                    u.h2[0] = __floats2half2_rn(acc[r][0], acc[r][1]);
                    u.h2[1] = __floats2half2_rn(acc[r][2], acc[r][3]);
                    *(float2*)&((__half*)Ov)[(size_t)row * F + tx * 4] = u.f2;
                }
            }
        }
    }

    if constexpr (EPI) {
        __syncthreads();
        if (tid < 2 * F) sRed[tid] = 0.f;
        __syncthreads();
        #pragma unroll
        for (int c = 0; c < 4; ++c) {
            atomicAdd(&sRed[tx * 4 + c], ls[c]);
            atomicAdd(&sRed[F + tx * 4 + c], lq[c]);
        }
        __syncthreads();
        if (tid < F) {
            atomicAdd(&sums[tid], sRed[tid]);
            atomicAdd(&sums[F + tid], sRed[F + tid]);
        }
    }
}

// ---------- CSR gather aggregation (fp16 H), fused self-loop+bias+ReLU+stats ----------
template<int F>
__global__ void k_aggf(const __half* __restrict__ Hh, const int* __restrict__ rs,
                       const int* __restrict__ rend, const int* __restrict__ csrc,
                       const float* __restrict__ dinv, const float* __restrict__ b,
                       float* __restrict__ A, float* __restrict__ sums, int n) {
    const int f = threadIdx.x;
    const float bf = b[f];
    float ls = 0.0f, lq = 0.0f;
    for (int d = blockIdx.x; d < n; d += gridDim.x) {
        const int beg = rs[d];
        const int end = rend[d];
        const float di = dinv[d];
        float acc = __half2float(Hh[(size_t)d * F + f]) * di;  // self loop
        int j = beg;
        for (; j + 3 < end; j += 4) {
            int s0 = csrc[j], s1 = csrc[j + 1], s2 = csrc[j + 2], s3 = csrc[j + 3];
            float w0 = dinv[s0], w1 = dinv[s1], w2 = dinv[s2], w3 = dinv[s3];
            float h0 = __half2float(Hh[(size_t)s0 * F + f]);
            float h1 = __half2float(Hh[(size_t)s1 * F + f]);
            float h2 = __half2float(Hh[(size_t)s2 * F + f]);
            float h3 = __half2float(Hh[(size_t)s3 * F + f]);
            acc = fmaf(h0, w0, acc);
            acc = fmaf(h1, w1, acc);
            acc = fmaf(h2, w2, acc);
            acc = fmaf(h3, w3, acc);
        }
        for (; j < end; ++j) {
            int s = csrc[j];
            acc = fmaf(__half2float(Hh[(size_t)s * F + f]), dinv[s], acc);
        }
        float v = fmaxf(fmaf(acc, di, bf), 0.0f);
        A[(size_t)d * F + f] = v;
        ls += v;
        lq += v * v;
    }
    atomicAdd(&sums[f], ls);
    atomicAdd(&sums[F + f], lq);
}

// ---------- BN fold ----------
__global__ void k_bnprep(const float* __restrict__ sums, const float* __restrict__ g,
                         const float* __restrict__ be, float* __restrict__ aff,
                         int F, float invn) {
    int f = threadIdx.x;
    if (f < F) {
        float mean = sums[f] * invn;
        float var = sums[F + f] * invn - mean * mean;
        float a = rsqrtf(var + BN_EPS) * g[f];
        aff[f] = a;
        aff[F + f] = be[f] - mean * a;
    }
}

// ---------- final 64->2 GEMM with input affine ----------
__global__ void k_gemm4(const float* __restrict__ X, const float* __restrict__ W,
                        const float* __restrict__ aff, float* __restrict__ H, int n) {
    int i = blockIdx.x * blockDim.x + threadIdx.x;
    if (i >= n) return;
    float a0 = 0.0f, a1 = 0.0f;
    #pragma unroll 8
    for (int k = 0; k < 64; ++k) {
        float v = X[i * 64 + k] * aff[k] + aff[64 + k];
        a0 = fmaf(v, W[2 * k], a0);
        a1 = fmaf(v, W[2 * k + 1], a1);
    }
    H[2 * i] = a0;
    H[2 * i + 1] = a1;
}

// ---------- final aggregation (F=2) + bias + log_softmax ----------
__global__ void k_last(const float* __restrict__ H, const int* __restrict__ rs,
                       const int* __restrict__ rend, const int* __restrict__ csrc,
                       const float* __restrict__ dinv, const float* __restrict__ b,
                       float* __restrict__ out, int n) {
    int d = blockIdx.x * blockDim.x + threadIdx.x;
    if (d >= n) return;
    const float di = dinv[d];
    float a0 = H[2 * d] * di, a1 = H[2 * d + 1] * di;
    const int beg = rs[d], end = rend[d];
    for (int j = beg; j < end; ++j) {
        int s = csrc[j];
        float w = dinv[s];
        a0 = fmaf(H[2 * s], w, a0);
        a1 = fmaf(H[2 * s + 1], w, a1);
    }
    float v0 = fmaf(a0, di, b[0]);
    float v1 = fmaf(a1, di, b[1]);
    float m = fmaxf(v0, v1);
    float l = logf(expf(v0 - m) + expf(v1 - m)) + m;
    out[2 * d] = v0 - l;
    out[2 * d + 1] = v1 - l;
}

extern "C" void kernel_launch(void* const* d_in, const int* in_sizes, int n_in,
                              void* d_out, int out_size, void* d_ws, size_t ws_size,
                              hipStream_t stream) {
    const float* x   = (const float*)d_in[0];
    const int*   ei  = (const int*)d_in[1];
    const float* W1  = (const float*)d_in[2];
    const float* b1  = (const float*)d_in[3];
    const float* g1  = (const float*)d_in[4];
    const float* be1 = (const float*)d_in[5];
    const float* W2  = (const float*)d_in[6];
    const float* b2  = (const float*)d_in[7];
    const float* g2  = (const float*)d_in[8];
    const float* be2 = (const float*)d_in[9];
    const float* W3  = (const float*)d_in[10];
    const float* b3  = (const float*)d_in[11];
    const float* g3  = (const float*)d_in[12];
    const float* be3 = (const float*)d_in[13];
    const float* W4  = (const float*)d_in[14];
    const float* b4  = (const float*)d_in[15];
    float* out = (float*)d_out;

    const int N = in_sizes[0] / 24;
    const int E = in_sizes[1] / 2;
    const int* srcI = ei;
    const int* dstI = ei + E;
    const int NB = (N + 127) >> 7;          // <= 1024 for N <= 131072

    // ---- workspace carve ----
    int* cnt   = (int*)d_ws;                 // N
    int* rs    = cnt + N;                    // N
    int* cur   = rs + N;                     // N
    int* csrc  = cur + N;                    // E
    int* bsum  = csrc + E;                   // 1024
    int* bcnt  = bsum + 1024;                // 1024
    int* bcur  = bcnt + 1024;                // 1024*32 (padded cursors)
    float* dinv = (float*)(bcur + 1024 * 32);// N
    float* Hbase = dinv + N;                 // N*128 f32 region (multi-use)
    float* A    = Hbase + (size_t)N * 128;   // N*128 f32
    float* S    = A + (size_t)N * 128;       // 1280 stats
    float* sums1 = S,        *aff1 = S + 256;
    float* sums2 = S + 512,  *aff2 = S + 768;
    float* sums3 = S + 1024, *aff3 = S + 1152;
    // aliases of Hbase (used at disjoint times, stream-ordered):
    int2*   pairs = (int2*)Hbase;            // 2E ints (12.8 MB) during CSR fill
    float*  XA    = Hbase;                   // N*24 f32 for layer-1 pre-agg
    __half* Hh    = (__half*)Hbase;          // N*128 fp16 for layers 2/3
    float*  LG    = Hbase;                   // N*2 logits for layer 4

    hipMemsetAsync(S, 0, 1280 * sizeof(float), stream);

    const int TB = 256;
    const int nb1024 = (N + 1023) / 1024;

    // ---- CSR build + dinv ----
    k_zero_i<<<(N + TB - 1) / TB, TB, 0, stream>>>(cnt, N);
    k_count<<<(E + TB - 1) / TB, TB, 0, stream>>>(dstI, cnt, E);
    k_dinv<<<(N + TB - 1) / TB, TB, 0, stream>>>(cnt, dinv, N);
    k_scan1<<<nb1024, 1024, 0, stream>>>(cnt, rs, bsum, N);
    k_scan2<<<1, 1024, 0, stream>>>(bsum, nb1024);
    k_scan3<<<(N + TB - 1) / TB, TB, 0, stream>>>(rs, cur, bsum, N);
    k_bcnt<<<(NB + TB - 1) / TB, TB, 0, stream>>>(cnt, bcnt, N, NB);
    k_bscan<<<1, 1024, 0, stream>>>(bcnt, bcur, NB);
    k_pass1<<<(E + TB - 1) / TB, TB, 0, stream>>>(srcI, dstI, bcur, pairs, E);
    k_pass2<<<(E + TB - 1) / TB, TB, 0, stream>>>(pairs, cur, csrc, E);
    // after k_pass2, cur[d] == row end

    // ----- layer 1: pre-aggregate x (24-wide), GEMM 24->128 + bias/relu/stats -----
    k_agg24<<<2048, 256, 0, stream>>>(x, rs, cur, csrc, dinv, XA, N);
    k_gemm2<24, 128, 4, false, true><<<1024, 256, 0, stream>>>(XA, W1, nullptr, A, b1, sums1, N);
    k_bnprep<<<1, 128, 0, stream>>>(sums1, g1, be1, aff1, 128, 1.0f / (float)N);

    // ----- layer 2: GEMM 128->128 (fp16 out), fp16 gather agg -----
    k_gemm2<128, 128, 4, true, false><<<1024, 256, 0, stream>>>(A, W2, aff1, Hh, nullptr, nullptr, N);
    k_aggf<128><<<4096, 128, 0, stream>>>(Hh, rs, cur, csrc, dinv, b2, A, sums2, N);
    k_bnprep<<<1, 128, 0, stream>>>(sums2, g2, be2, aff2, 128, 1.0f / (float)N);

    // ----- layer 3: GEMM 128->64 (fp16 out), fp16 gather agg -----
    k_gemm2<128, 64, 2, true, false><<<1024, 256, 0, stream>>>(A, W3, aff2, Hh, nullptr, nullptr, N);
    k_aggf<64><<<4096, 64, 0, stream>>>(Hh, rs, cur, csrc, dinv, b3, A, sums3, N);
    k_bnprep<<<1, 64, 0, stream>>>(sums3, g3, be3, aff3, 64, 1.0f / (float)N);

    // ----- layer 4: 64 -> 2, log_softmax -----
    k_gemm4<<<(N + TB - 1) / TB, TB, 0, stream>>>(A, W4, aff3, LG, N);
    k_last<<<(N + TB - 1) / TB, TB, 0, stream>>>(LG, rs, cur, csrc, dinv, b4, out, N);
}

// Round 7
// 680.628 us; speedup vs baseline: 1.7467x; 1.1926x over previous
//
#include <hip/hip_runtime.h>
#include <hip/hip_fp16.h>

#define BN_EPS 1e-5f

// ---------- degree count (int) ----------
__global__ void k_zero_i(int* __restrict__ p, int n) {
    int i = blockIdx.x * blockDim.x + threadIdx.x;
    if (i < n) p[i] = 0;
}

__global__ void k_count(const int* __restrict__ dst, int* __restrict__ cnt, int E) {
    int e = blockIdx.x * blockDim.x + threadIdx.x;
    if (e < E) atomicAdd(&cnt[dst[e]], 1);
}

__global__ void k_dinv(const int* __restrict__ cnt, float* __restrict__ dinv, int n) {
    int i = blockIdx.x * blockDim.x + threadIdx.x;
    if (i < n) dinv[i] = rsqrtf((float)(cnt[i] + 1));   // +1 self loop
}

// ---------- exclusive scan (two-level) ----------
__global__ void k_scan1(const int* __restrict__ cnt, int* __restrict__ rs,
                        int* __restrict__ bsum, int n) {
    __shared__ int sh[1024];
    const int t = threadIdx.x;
    const int gid = blockIdx.x * 1024 + t;
    int v = (gid < n) ? cnt[gid] : 0;
    sh[t] = v;
    __syncthreads();
    for (int off = 1; off < 1024; off <<= 1) {
        int u = (t >= off) ? sh[t - off] : 0;
        __syncthreads();
        sh[t] += u;
        __syncthreads();
    }
    if (gid < n) rs[gid] = sh[t] - v;       // exclusive
    if (t == 1023) bsum[blockIdx.x] = sh[1023];
}

__global__ void k_scan2(int* __restrict__ bsum, int nb) {
    __shared__ int sh[1024];
    const int t = threadIdx.x;
    int v = (t < nb) ? bsum[t] : 0;
    sh[t] = v;
    __syncthreads();
    for (int off = 1; off < 1024; off <<= 1) {
        int u = (t >= off) ? sh[t - off] : 0;
        __syncthreads();
        sh[t] += u;
        __syncthreads();
    }
    if (t < nb) bsum[t] = sh[t] - v;        // exclusive
}

__global__ void k_scan3(int* __restrict__ rs, int* __restrict__ cur,
                        const int* __restrict__ bsum, int n) {
    int i = blockIdx.x * blockDim.x + threadIdx.x;
    if (i < n) {
        int v = rs[i] + bsum[i >> 10];
        rs[i] = v;
        cur[i] = v;
    }
}

// ---------- bucketed CSR fill, PADDED cursors (1 per 128B line) ----------
__global__ void k_bcnt(const int* __restrict__ cnt, int* __restrict__ bcnt,
                       int n, int nb) {
    int b = blockIdx.x * blockDim.x + threadIdx.x;
    if (b >= nb) return;
    int s = 0;
    int base = b << 7;
    for (int k = 0; k < 128; ++k) {
        int id = base + k;
        if (id < n) s += cnt[id];
    }
    bcnt[b] = s;
}

__global__ void k_bscan(const int* __restrict__ bcnt, int* __restrict__ bcur, int nb) {
    __shared__ int sh[1024];
    const int t = threadIdx.x;
    int v = (t < nb) ? bcnt[t] : 0;
    sh[t] = v;
    __syncthreads();
    for (int off = 1; off < 1024; off <<= 1) {
        int u = (t >= off) ? sh[t - off] : 0;
        __syncthreads();
        sh[t] += u;
        __syncthreads();
    }
    if (t < nb) bcur[t * 32] = sh[t] - v;   // exclusive, padded stride
}

__global__ void k_pass1(const int* __restrict__ src, const int* __restrict__ dst,
                        int* __restrict__ bcur, int2* __restrict__ pairs, int E) {
    int e = blockIdx.x * blockDim.x + threadIdx.x;
    if (e < E) {
        int d = dst[e];
        int pos = atomicAdd(&bcur[(d >> 7) * 32], 1);
        pairs[pos] = make_int2(d, src[e]);
    }
}

__global__ void k_pass2(const int2* __restrict__ pairs, int* __restrict__ cur,
                        int* __restrict__ csrc, int E) {
    int e = blockIdx.x * blockDim.x + threadIdx.x;
    if (e < E) {
        int2 p = pairs[e];
        int pos = atomicAdd(&cur[p.x], 1);
        csrc[pos] = p.y;
    }
}

// ---------- x -> fp16 convert ----------
__global__ void k_x2h(const float* __restrict__ x, __half* __restrict__ xh, int total4) {
    int i = blockIdx.x * blockDim.x + threadIdx.x;
    int idx = i * 4;
    if (idx < total4 * 4) {
        float4 v = *(const float4*)&x[idx];
        union { uint2 u; __half2 h[2]; } o;
        o.h[0] = __floats2half2_rn(v.x, v.y);
        o.h[1] = __floats2half2_rn(v.z, v.w);
        *(uint2*)&xh[idx] = o.u;
    }
}

// ---------- layer-1 pre-aggregation on fp16 x (24-wide) ----------
__global__ void k_agg24h(const __half* __restrict__ xh, const int* __restrict__ rs,
                         const int* __restrict__ rend, const int* __restrict__ csrc,
                         const float* __restrict__ dinv, float* __restrict__ XA, int n) {
    const int g = threadIdx.x >> 3;
    const int j = threadIdx.x & 7;
    const bool act = (j < 6);
    union U { uint2 u; __half2 h[2]; };
    for (int d = blockIdx.x * 32 + g; d < n; d += gridDim.x * 32) {
        const float di = dinv[d];
        const int beg = rs[d], end = rend[d];
        float4 acc = make_float4(0.f, 0.f, 0.f, 0.f);
        if (act) {
            U u; u.u = *(const uint2*)&xh[(size_t)d * 24 + 4 * j];
            float2 f0 = __half22float2(u.h[0]), f1 = __half22float2(u.h[1]);
            acc.x = f0.x * di; acc.y = f0.y * di; acc.z = f1.x * di; acc.w = f1.y * di;
        }
        int e = beg;
        for (; e + 3 < end; e += 4) {
            int s0 = csrc[e], s1 = csrc[e + 1], s2 = csrc[e + 2], s3 = csrc[e + 3];
            float w0 = dinv[s0], w1 = dinv[s1], w2 = dinv[s2], w3 = dinv[s3];
            if (act) {
                U u0, u1, u2, u3;
                u0.u = *(const uint2*)&xh[(size_t)s0 * 24 + 4 * j];
                u1.u = *(const uint2*)&xh[(size_t)s1 * 24 + 4 * j];
                u2.u = *(const uint2*)&xh[(size_t)s2 * 24 + 4 * j];
                u3.u = *(const uint2*)&xh[(size_t)s3 * 24 + 4 * j];
                float2 a0 = __half22float2(u0.h[0]), b0 = __half22float2(u0.h[1]);
                float2 a1 = __half22float2(u1.h[0]), b1 = __half22float2(u1.h[1]);
                float2 a2 = __half22float2(u2.h[0]), b2 = __half22float2(u2.h[1]);
                float2 a3 = __half22float2(u3.h[0]), b3 = __half22float2(u3.h[1]);
                acc.x = fmaf(a0.x, w0, acc.x); acc.y = fmaf(a0.y, w0, acc.y);
                acc.z = fmaf(b0.x, w0, acc.z); acc.w = fmaf(b0.y, w0, acc.w);
                acc.x = fmaf(a1.x, w1, acc.x); acc.y = fmaf(a1.y, w1, acc.y);
                acc.z = fmaf(b1.x, w1, acc.z); acc.w = fmaf(b1.y, w1, acc.w);
                acc.x = fmaf(a2.x, w2, acc.x); acc.y = fmaf(a2.y, w2, acc.y);
                acc.z = fmaf(b2.x, w2, acc.z); acc.w = fmaf(b2.y, w2, acc.w);
                acc.x = fmaf(a3.x, w3, acc.x); acc.y = fmaf(a3.y, w3, acc.y);
                acc.z = fmaf(b3.x, w3, acc.z); acc.w = fmaf(b3.y, w3, acc.w);
            }
        }
        for (; e < end; ++e) {
            int s = csrc[e];
            float w = dinv[s];
            if (act) {
                U u; u.u = *(const uint2*)&xh[(size_t)s * 24 + 4 * j];
                float2 f0 = __half22float2(u.h[0]), f1 = __half22float2(u.h[1]);
                acc.x = fmaf(f0.x, w, acc.x); acc.y = fmaf(f0.y, w, acc.y);
                acc.z = fmaf(f1.x, w, acc.z); acc.w = fmaf(f1.y, w, acc.w);
            }
        }
        if (act) {
            acc.x *= di; acc.y *= di; acc.z *= di; acc.w *= di;
            *(float4*)&XA[(size_t)d * 24 + 4 * j] = acc;
        }
    }
}

// ---------- GEMM: out = (X*aff_a + aff_c) @ W ----------
template<int K, int F, int RT, bool AFF, bool EPI>
__global__ __launch_bounds__(256) void k_gemm2(const float* __restrict__ X,
        const float* __restrict__ W, const float* __restrict__ aff,
        void* __restrict__ Ov, const float* __restrict__ b,
        float* __restrict__ sums, int n) {
    constexpr int COLG = F / 4;
    constexpr int ROWG = 256 / COLG;
    constexpr int TR = ROWG * RT;
    __shared__ float sW[K * F];
    __shared__ float sX[TR * K];
    __shared__ float sRed[2 * F];
    const int tid = threadIdx.x;
    const int tx = tid % COLG;
    const int ty = tid / COLG;

    for (int i = tid * 4; i < K * F; i += 1024)
        *(float4*)&sW[i] = *(const float4*)&W[i];

    float4 bv;
    float ls[4], lq[4];
    if constexpr (EPI) {
        bv = *(const float4*)&b[tx * 4];
        #pragma unroll
        for (int c = 0; c < 4; ++c) { ls[c] = 0.f; lq[c] = 0.f; }
    }

    const int ntiles = (n + TR - 1) / TR;
    for (int tile = blockIdx.x; tile < ntiles; tile += gridDim.x) {
        const int r0 = tile * TR;
        __syncthreads();
        for (int i = tid * 4; i < TR * K; i += 1024) {
            const int row = i / K;
            const int kk = i % K;
            float4 v;
            if (r0 + row < n) {
                v = *(const float4*)&X[(size_t)(r0 + row) * K + kk];
                if constexpr (AFF) {
                    v.x = fmaf(v.x, aff[kk],     aff[K + kk]);
                    v.y = fmaf(v.y, aff[kk + 1], aff[K + kk + 1]);
                    v.z = fmaf(v.z, aff[kk + 2], aff[K + kk + 2]);
                    v.w = fmaf(v.w, aff[kk + 3], aff[K + kk + 3]);
                }
            } else {
                v = make_float4(0.f, 0.f, 0.f, 0.f);
            }
            *(float4*)&sX[i] = v;
        }
        __syncthreads();

        float acc[RT][4];
        #pragma unroll
        for (int r = 0; r < RT; ++r)
            #pragma unroll
            for (int c = 0; c < 4; ++c) acc[r][c] = 0.0f;

        for (int k4 = 0; k4 < K; k4 += 4) {
            float xk[RT][4];
            #pragma unroll
            for (int r = 0; r < RT; ++r) {
                float4 t = *(const float4*)&sX[(ty * RT + r) * K + k4];
                xk[r][0] = t.x; xk[r][1] = t.y; xk[r][2] = t.z; xk[r][3] = t.w;
            }
            float4 wv[4];
            #pragma unroll
            for (int kk = 0; kk < 4; ++kk)
                wv[kk] = *(const float4*)&sW[(k4 + kk) * F + tx * 4];
            #pragma unroll
            for (int kk = 0; kk < 4; ++kk)
                #pragma unroll
                for (int r = 0; r < RT; ++r) {
                    const float xr = xk[r][kk];
                    acc[r][0] = fmaf(xr, wv[kk].x, acc[r][0]);
                    acc[r][1] = fmaf(xr, wv[kk].y, acc[r][1]);
                    acc[r][2] = fmaf(xr, wv[kk].z, acc[r][2]);
                    acc[r][3] = fmaf(xr, wv[kk].w, acc[r][3]);
                }
        }

        #pragma unroll
        for (int r = 0; r < RT; ++r) {
            const int row = r0 + ty * RT + r;
            if (row < n) {
                if constexpr (EPI) {
                    float4 o;
                    o.x = fmaxf(acc[r][0] + bv.x, 0.f);
                    o.y = fmaxf(acc[r][1] + bv.y, 0.f);
                    o.z = fmaxf(acc[r][2] + bv.z, 0.f);
                    o.w = fmaxf(acc[r][3] + bv.w, 0.f);
                    ls[0] += o.x; lq[0] += o.x * o.x;
                    ls[1] += o.y; lq[1] += o.y * o.y;
                    ls[2] += o.z; lq[2] += o.z * o.z;
                    ls[3] += o.w; lq[3] += o.w * o.w;
                    *(float4*)&((float*)Ov)[(size_t)row * F + tx * 4] = o;
                } else {
                    union { float2 f2; __half2 h2[2]; } u;
                    u.h2[0] = __floats2half2_rn(acc[r][0], acc[r][1]);
                    u.h2[1] = __floats2half2_rn(acc[r][2], acc[r][3]);
                    *(float2*)&((__half*)Ov)[(size_t)row * F + tx * 4] = u.f2;
                }
            }
        }
    }

    if constexpr (EPI) {
        __syncthreads();
        if (tid < 2 * F) sRed[tid] = 0.f;
        __syncthreads();
        #pragma unroll
        for (int c = 0; c < 4; ++c) {
            atomicAdd(&sRed[tx * 4 + c], ls[c]);
            atomicAdd(&sRed[F + tx * 4 + c], lq[c]);
        }
        __syncthreads();
        if (tid < F) {
            atomicAdd(&sums[tid], sRed[tid]);
            atomicAdd(&sums[F + tid], sRed[F + tid]);
        }
    }
}

// ---------- half2 CSR gather aggregation, wave-per-node, 8-deep unroll ----------
// F=128: 64 lanes x half2 = full row, 1 node/wave. F=64: 32 lanes/node, 2 nodes/wave.
template<int F>
__global__ __launch_bounds__(256) void k_aggh(const __half2* __restrict__ H2,
        const int* __restrict__ rs, const int* __restrict__ rend,
        const int* __restrict__ csrc, const float* __restrict__ dinv,
        const float* __restrict__ b, float* __restrict__ A,
        float* __restrict__ sums, int n) {
    constexpr int LPN = F / 2;           // lanes per node
    constexpr int NPW = 64 / LPN;        // nodes per wave
    __shared__ float sR[2 * F];
    const int tid = threadIdx.x;
    const int lane = tid & 63;
    const int wid = tid >> 6;
    const int sub = lane / LPN;
    const int fl = lane % LPN;
    const float2 bv = make_float2(b[2 * fl], b[2 * fl + 1]);
    const int gw = blockIdx.x * 4 + wid;
    const int nw = gridDim.x * 4;
    float ls0 = 0.f, lq0 = 0.f, ls1 = 0.f, lq1 = 0.f;

    for (int d = gw * NPW + sub; d < n; d += nw * NPW) {
        const int beg = rs[d], end = rend[d];
        const float di = dinv[d];
        float2 h = __half22float2(H2[(size_t)d * LPN + fl]);
        float ax = h.x * di, ay = h.y * di;     // self loop (x di again below)
        int j = beg;
        for (; j + 7 < end; j += 8) {
            int s[8];
            #pragma unroll
            for (int k = 0; k < 8; ++k) s[k] = csrc[j + k];
            float w[8]; __half2 hv[8];
            #pragma unroll
            for (int k = 0; k < 8; ++k) {
                w[k] = dinv[s[k]];
                hv[k] = H2[(size_t)s[k] * LPN + fl];
            }
            #pragma unroll
            for (int k = 0; k < 8; ++k) {
                float2 f = __half22float2(hv[k]);
                ax = fmaf(f.x, w[k], ax);
                ay = fmaf(f.y, w[k], ay);
            }
        }
        for (; j + 3 < end; j += 4) {
            int s[4];
            #pragma unroll
            for (int k = 0; k < 4; ++k) s[k] = csrc[j + k];
            float w[4]; __half2 hv[4];
            #pragma unroll
            for (int k = 0; k < 4; ++k) {
                w[k] = dinv[s[k]];
                hv[k] = H2[(size_t)s[k] * LPN + fl];
            }
            #pragma unroll
            for (int k = 0; k < 4; ++k) {
                float2 f = __half22float2(hv[k]);
                ax = fmaf(f.x, w[k], ax);
                ay = fmaf(f.y, w[k], ay);
            }
        }
        for (; j < end; ++j) {
            int s = csrc[j];
            float w = dinv[s];
            float2 f = __half22float2(H2[(size_t)s * LPN + fl]);
            ax = fmaf(f.x, w, ax);
            ay = fmaf(f.y, w, ay);
        }
        float vx = fmaxf(fmaf(ax, di, bv.x), 0.f);
        float vy = fmaxf(fmaf(ay, di, bv.y), 0.f);
        *(float2*)&A[(size_t)d * F + 2 * fl] = make_float2(vx, vy);
        ls0 += vx; lq0 += vx * vx;
        ls1 += vy; lq1 += vy * vy;
    }

    if (tid < 2 * F) sR[tid] = 0.f;
    __syncthreads();
    atomicAdd(&sR[2 * fl], ls0);
    atomicAdd(&sR[2 * fl + 1], ls1);
    atomicAdd(&sR[F + 2 * fl], lq0);
    atomicAdd(&sR[F + 2 * fl + 1], lq1);
    __syncthreads();
    if (tid < 2 * F) atomicAdd(&sums[tid], sR[tid]);
}

// ---------- BN fold ----------
__global__ void k_bnprep(const float* __restrict__ sums, const float* __restrict__ g,
                         const float* __restrict__ be, float* __restrict__ aff,
                         int F, float invn) {
    int f = threadIdx.x;
    if (f < F) {
        float mean = sums[f] * invn;
        float var = sums[F + f] * invn - mean * mean;
        float a = rsqrtf(var + BN_EPS) * g[f];
        aff[f] = a;
        aff[F + f] = be[f] - mean * a;
    }
}

// ---------- final 64->2 GEMM with input affine ----------
__global__ void k_gemm4(const float* __restrict__ X, const float* __restrict__ W,
                        const float* __restrict__ aff, float* __restrict__ H, int n) {
    int i = blockIdx.x * blockDim.x + threadIdx.x;
    if (i >= n) return;
    float a0 = 0.0f, a1 = 0.0f;
    #pragma unroll 8
    for (int k = 0; k < 64; ++k) {
        float v = X[i * 64 + k] * aff[k] + aff[64 + k];
        a0 = fmaf(v, W[2 * k], a0);
        a1 = fmaf(v, W[2 * k + 1], a1);
    }
    H[2 * i] = a0;
    H[2 * i + 1] = a1;
}

// ---------- final aggregation (F=2) + bias + log_softmax ----------
__global__ void k_last(const float* __restrict__ H, const int* __restrict__ rs,
                       const int* __restrict__ rend, const int* __restrict__ csrc,
                       const float* __restrict__ dinv, const float* __restrict__ b,
                       float* __restrict__ out, int n) {
    int d = blockIdx.x * blockDim.x + threadIdx.x;
    if (d >= n) return;
    const float di = dinv[d];
    float a0 = H[2 * d] * di, a1 = H[2 * d + 1] * di;
    const int beg = rs[d], end = rend[d];
    for (int j = beg; j < end; ++j) {
        int s = csrc[j];
        float w = dinv[s];
        a0 = fmaf(H[2 * s], w, a0);
        a1 = fmaf(H[2 * s + 1], w, a1);
    }
    float v0 = fmaf(a0, di, b[0]);
    float v1 = fmaf(a1, di, b[1]);
    float m = fmaxf(v0, v1);
    float l = logf(expf(v0 - m) + expf(v1 - m)) + m;
    out[2 * d] = v0 - l;
    out[2 * d + 1] = v1 - l;
}

extern "C" void kernel_launch(void* const* d_in, const int* in_sizes, int n_in,
                              void* d_out, int out_size, void* d_ws, size_t ws_size,
                              hipStream_t stream) {
    const float* x   = (const float*)d_in[0];
    const int*   ei  = (const int*)d_in[1];
    const float* W1  = (const float*)d_in[2];
    const float* b1  = (const float*)d_in[3];
    const float* g1  = (const float*)d_in[4];
    const float* be1 = (const float*)d_in[5];
    const float* W2  = (const float*)d_in[6];
    const float* b2  = (const float*)d_in[7];
    const float* g2  = (const float*)d_in[8];
    const float* be2 = (const float*)d_in[9];
    const float* W3  = (const float*)d_in[10];
    const float* b3  = (const float*)d_in[11];
    const float* g3  = (const float*)d_in[12];
    const float* be3 = (const float*)d_in[13];
    const float* W4  = (const float*)d_in[14];
    const float* b4  = (const float*)d_in[15];
    float* out = (float*)d_out;

    const int N = in_sizes[0] / 24;
    const int E = in_sizes[1] / 2;
    const int* srcI = ei;
    const int* dstI = ei + E;
    const int NB = (N + 127) >> 7;

    // ---- workspace carve ----
    int* cnt   = (int*)d_ws;                 // N
    int* rs    = cnt + N;                    // N
    int* cur   = rs + N;                     // N
    int* csrc  = cur + N;                    // E
    int* bsum  = csrc + E;                   // 1024
    int* bcnt  = bsum + 1024;                // 1024
    int* bcur  = bcnt + 1024;                // 1024*32 (padded cursors)
    float* dinv = (float*)(bcur + 1024 * 32);// N
    float* Hbase = dinv + N;                 // N*128 f32 region (multi-use)
    float* A    = Hbase + (size_t)N * 128;   // N*128 f32
    float* S    = A + (size_t)N * 128;       // 1280 stats
    float* sums1 = S,        *aff1 = S + 256;
    float* sums2 = S + 512,  *aff2 = S + 768;
    float* sums3 = S + 1024, *aff3 = S + 1152;
    // aliases of Hbase (disjoint lifetimes, stream-ordered):
    int2*   pairs = (int2*)Hbase;            // 2E ints during CSR fill
    float*  XA    = Hbase;                   // N*24 f32 (layer-1 pre-agg out)
    __half* Hh    = (__half*)Hbase;          // N*128 fp16 (layers 2/3)
    float*  LG    = Hbase;                   // N*2 logits (layer 4)
    // alias of A (dead until gemm1 writes it):
    __half* xh    = (__half*)A;              // N*24 fp16 copy of x

    hipMemsetAsync(S, 0, 1280 * sizeof(float), stream);

    const int TB = 256;
    const int nb1024 = (N + 1023) / 1024;

    // ---- CSR build + dinv ----
    k_zero_i<<<(N + TB - 1) / TB, TB, 0, stream>>>(cnt, N);
    k_count<<<(E + TB - 1) / TB, TB, 0, stream>>>(dstI, cnt, E);
    k_dinv<<<(N + TB - 1) / TB, TB, 0, stream>>>(cnt, dinv, N);
    k_scan1<<<nb1024, 1024, 0, stream>>>(cnt, rs, bsum, N);
    k_scan2<<<1, 1024, 0, stream>>>(bsum, nb1024);
    k_scan3<<<(N + TB - 1) / TB, TB, 0, stream>>>(rs, cur, bsum, N);
    k_bcnt<<<(NB + TB - 1) / TB, TB, 0, stream>>>(cnt, bcnt, N, NB);
    k_bscan<<<1, 1024, 0, stream>>>(bcnt, bcur, NB);
    k_pass1<<<(E + TB - 1) / TB, TB, 0, stream>>>(srcI, dstI, bcur, pairs, E);
    k_pass2<<<(E + TB - 1) / TB, TB, 0, stream>>>(pairs, cur, csrc, E);
    // after k_pass2, cur[d] == row end

    // ----- layer 1: fp16 x, pre-aggregate (24-wide), GEMM 24->128 + epilogue -----
    k_x2h<<<(N * 24 / 4 + TB - 1) / TB, TB, 0, stream>>>(x, xh, N * 24 / 4);
    k_agg24h<<<2048, 256, 0, stream>>>(xh, rs, cur, csrc, dinv, XA, N);
    k_gemm2<24, 128, 4, false, true><<<1024, 256, 0, stream>>>(XA, W1, nullptr, A, b1, sums1, N);
    k_bnprep<<<1, 128, 0, stream>>>(sums1, g1, be1, aff1, 128, 1.0f / (float)N);

    // ----- layer 2: GEMM 128->128 (fp16 out), half2 gather agg -----
    k_gemm2<128, 128, 4, true, false><<<1024, 256, 0, stream>>>(A, W2, aff1, Hh, nullptr, nullptr, N);
    k_aggh<128><<<2048, 256, 0, stream>>>((const __half2*)Hh, rs, cur, csrc, dinv, b2, A, sums2, N);
    k_bnprep<<<1, 128, 0, stream>>>(sums2, g2, be2, aff2, 128, 1.0f / (float)N);

    // ----- layer 3: GEMM 128->64 (fp16 out), half2 gather agg -----
    k_gemm2<128, 64, 2, true, false><<<1024, 256, 0, stream>>>(A, W3, aff2, Hh, nullptr, nullptr, N);
    k_aggh<64><<<2048, 256, 0, stream>>>((const __half2*)Hh, rs, cur, csrc, dinv, b3, A, sums3, N);
    k_bnprep<<<1, 64, 0, stream>>>(sums3, g3, be3, aff3, 64, 1.0f / (float)N);

    // ----- layer 4: 64 -> 2, log_softmax -----
    k_gemm4<<<(N + TB - 1) / TB, TB, 0, stream>>>(A, W4, aff3, LG, N);
    k_last<<<(N + TB - 1) / TB, TB, 0, stream>>>(LG, rs, cur, csrc, dinv, b4, out, N);
}

// Round 8
// 553.184 us; speedup vs baseline: 2.1491x; 1.2304x over previous
//
#include <hip/hip_runtime.h>
#include <hip/hip_fp16.h>

#define BN_EPS 1e-5f

// ---------- degree count (int) ----------
__global__ void k_zero_i(int* __restrict__ p, int n) {
    int i = blockIdx.x * blockDim.x + threadIdx.x;
    if (i < n) p[i] = 0;
}

__global__ void k_count(const int* __restrict__ dst, int* __restrict__ cnt, int E) {
    int e = blockIdx.x * blockDim.x + threadIdx.x;
    if (e < E) atomicAdd(&cnt[dst[e]], 1);
}

__global__ void k_dinv(const int* __restrict__ cnt, float* __restrict__ dinv, int n) {
    int i = blockIdx.x * blockDim.x + threadIdx.x;
    if (i < n) dinv[i] = rsqrtf((float)(cnt[i] + 1));   // +1 self loop
}

// ---------- exclusive scan (two-level) ----------
__global__ void k_scan1(const int* __restrict__ cnt, int* __restrict__ rs,
                        int* __restrict__ bsum, int n) {
    __shared__ int sh[1024];
    const int t = threadIdx.x;
    const int gid = blockIdx.x * 1024 + t;
    int v = (gid < n) ? cnt[gid] : 0;
    sh[t] = v;
    __syncthreads();
    for (int off = 1; off < 1024; off <<= 1) {
        int u = (t >= off) ? sh[t - off] : 0;
        __syncthreads();
        sh[t] += u;
        __syncthreads();
    }
    if (gid < n) rs[gid] = sh[t] - v;       // exclusive
    if (t == 1023) bsum[blockIdx.x] = sh[1023];
}

__global__ void k_scan2(int* __restrict__ bsum, int nb) {
    __shared__ int sh[1024];
    const int t = threadIdx.x;
    int v = (t < nb) ? bsum[t] : 0;
    sh[t] = v;
    __syncthreads();
    for (int off = 1; off < 1024; off <<= 1) {
        int u = (t >= off) ? sh[t - off] : 0;
        __syncthreads();
        sh[t] += u;
        __syncthreads();
    }
    if (t < nb) bsum[t] = sh[t] - v;        // exclusive
}

__global__ void k_scan3(int* __restrict__ rs, int* __restrict__ cur,
                        const int* __restrict__ bsum, int n) {
    int i = blockIdx.x * blockDim.x + threadIdx.x;
    if (i < n) {
        int v = rs[i] + bsum[i >> 10];
        rs[i] = v;
        cur[i] = v;
    }
}

// ---------- XCD-affine direct CSR fill ----------
// blockIdx%8 ~ XCD (round-robin dispatch heuristic; perf-only assumption).
// Edge list split into chunks; each chunk scanned by 8 blocks, one per XCD;
// a block takes only edges whose dst-bucket (128 nodes) maps to its XCD.
// => all writers of a csrc/cur cache line are on ONE XCD -> L2 write merge,
// no cross-XCD partial-line HBM flushes (R7 lesson: pairs scatter had 7x WA).
__global__ void k_fillx(const int* __restrict__ src, const int* __restrict__ dst,
                        int* __restrict__ cur, int* __restrict__ csrc,
                        int E, int nchunk) {
    const int chunk = blockIdx.x >> 3;
    const int myx = blockIdx.x & 7;
    const int per = (E + nchunk - 1) / nchunk;
    const int lo = chunk * per;
    const int hi = min(lo + per, E);
    for (int e = lo + threadIdx.x; e < hi; e += blockDim.x) {
        int d = dst[e];
        if (((d >> 7) & 7) == myx) {
            int pos = atomicAdd(&cur[d], 1);
            csrc[pos] = src[e];
        }
    }
}

// ---------- x -> fp16 convert ----------
__global__ void k_x2h(const float* __restrict__ x, __half* __restrict__ xh, int total4) {
    int i = blockIdx.x * blockDim.x + threadIdx.x;
    int idx = i * 4;
    if (idx < total4 * 4) {
        float4 v = *(const float4*)&x[idx];
        union { uint2 u; __half2 h[2]; } o;
        o.h[0] = __floats2half2_rn(v.x, v.y);
        o.h[1] = __floats2half2_rn(v.z, v.w);
        *(uint2*)&xh[idx] = o.u;
    }
}

// ---------- layer-1 pre-aggregation on fp16 x (24-wide) ----------
__global__ void k_agg24h(const __half* __restrict__ xh, const int* __restrict__ rs,
                         const int* __restrict__ rend, const int* __restrict__ csrc,
                         const float* __restrict__ dinv, float* __restrict__ XA, int n) {
    const int g = threadIdx.x >> 3;
    const int j = threadIdx.x & 7;
    const bool act = (j < 6);
    union U { uint2 u; __half2 h[2]; };
    for (int d = blockIdx.x * 32 + g; d < n; d += gridDim.x * 32) {
        const float di = dinv[d];
        const int beg = rs[d], end = rend[d];
        float4 acc = make_float4(0.f, 0.f, 0.f, 0.f);
        if (act) {
            U u; u.u = *(const uint2*)&xh[(size_t)d * 24 + 4 * j];
            float2 f0 = __half22float2(u.h[0]), f1 = __half22float2(u.h[1]);
            acc.x = f0.x * di; acc.y = f0.y * di; acc.z = f1.x * di; acc.w = f1.y * di;
        }
        int e = beg;
        for (; e + 3 < end; e += 4) {
            int s0 = csrc[e], s1 = csrc[e + 1], s2 = csrc[e + 2], s3 = csrc[e + 3];
            float w0 = dinv[s0], w1 = dinv[s1], w2 = dinv[s2], w3 = dinv[s3];
            if (act) {
                U u0, u1, u2, u3;
                u0.u = *(const uint2*)&xh[(size_t)s0 * 24 + 4 * j];
                u1.u = *(const uint2*)&xh[(size_t)s1 * 24 + 4 * j];
                u2.u = *(const uint2*)&xh[(size_t)s2 * 24 + 4 * j];
                u3.u = *(const uint2*)&xh[(size_t)s3 * 24 + 4 * j];
                float2 a0 = __half22float2(u0.h[0]), b0 = __half22float2(u0.h[1]);
                float2 a1 = __half22float2(u1.h[0]), b1 = __half22float2(u1.h[1]);
                float2 a2 = __half22float2(u2.h[0]), b2 = __half22float2(u2.h[1]);
                float2 a3 = __half22float2(u3.h[0]), b3 = __half22float2(u3.h[1]);
                acc.x = fmaf(a0.x, w0, acc.x); acc.y = fmaf(a0.y, w0, acc.y);
                acc.z = fmaf(b0.x, w0, acc.z); acc.w = fmaf(b0.y, w0, acc.w);
                acc.x = fmaf(a1.x, w1, acc.x); acc.y = fmaf(a1.y, w1, acc.y);
                acc.z = fmaf(b1.x, w1, acc.z); acc.w = fmaf(b1.y, w1, acc.w);
                acc.x = fmaf(a2.x, w2, acc.x); acc.y = fmaf(a2.y, w2, acc.y);
                acc.z = fmaf(b2.x, w2, acc.z); acc.w = fmaf(b2.y, w2, acc.w);
                acc.x = fmaf(a3.x, w3, acc.x); acc.y = fmaf(a3.y, w3, acc.y);
                acc.z = fmaf(b3.x, w3, acc.z); acc.w = fmaf(b3.y, w3, acc.w);
            }
        }
        for (; e < end; ++e) {
            int s = csrc[e];
            float w = dinv[s];
            if (act) {
                U u; u.u = *(const uint2*)&xh[(size_t)s * 24 + 4 * j];
                float2 f0 = __half22float2(u.h[0]), f1 = __half22float2(u.h[1]);
                acc.x = fmaf(f0.x, w, acc.x); acc.y = fmaf(f0.y, w, acc.y);
                acc.z = fmaf(f1.x, w, acc.z); acc.w = fmaf(f1.y, w, acc.w);
            }
        }
        if (act) {
            acc.x *= di; acc.y *= di; acc.z *= di; acc.w *= di;
            *(float4*)&XA[(size_t)d * 24 + 4 * j] = acc;
        }
    }
}

// ---------- GEMM: out = (X*aff_a + aff_c) @ W ----------
template<int K, int F, int RT, bool AFF, bool EPI>
__global__ __launch_bounds__(256) void k_gemm2(const float* __restrict__ X,
        const float* __restrict__ W, const float* __restrict__ aff,
        void* __restrict__ Ov, const float* __restrict__ b,
        float* __restrict__ sums, int n) {
    constexpr int COLG = F / 4;
    constexpr int ROWG = 256 / COLG;
    constexpr int TR = ROWG * RT;
    __shared__ float sW[K * F];
    __shared__ float sX[TR * K];
    __shared__ float sRed[2 * F];
    const int tid = threadIdx.x;
    const int tx = tid % COLG;
    const int ty = tid / COLG;

    for (int i = tid * 4; i < K * F; i += 1024)
        *(float4*)&sW[i] = *(const float4*)&W[i];

    float4 bv;
    float ls[4], lq[4];
    if constexpr (EPI) {
        bv = *(const float4*)&b[tx * 4];
        #pragma unroll
        for (int c = 0; c < 4; ++c) { ls[c] = 0.f; lq[c] = 0.f; }
    }

    const int ntiles = (n + TR - 1) / TR;
    for (int tile = blockIdx.x; tile < ntiles; tile += gridDim.x) {
        const int r0 = tile * TR;
        __syncthreads();
        for (int i = tid * 4; i < TR * K; i += 1024) {
            const int row = i / K;
            const int kk = i % K;
            float4 v;
            if (r0 + row < n) {
                v = *(const float4*)&X[(size_t)(r0 + row) * K + kk];
                if constexpr (AFF) {
                    v.x = fmaf(v.x, aff[kk],     aff[K + kk]);
                    v.y = fmaf(v.y, aff[kk + 1], aff[K + kk + 1]);
                    v.z = fmaf(v.z, aff[kk + 2], aff[K + kk + 2]);
                    v.w = fmaf(v.w, aff[kk + 3], aff[K + kk + 3]);
                }
            } else {
                v = make_float4(0.f, 0.f, 0.f, 0.f);
            }
            *(float4*)&sX[i] = v;
        }
        __syncthreads();

        float acc[RT][4];
        #pragma unroll
        for (int r = 0; r < RT; ++r)
            #pragma unroll
            for (int c = 0; c < 4; ++c) acc[r][c] = 0.0f;

        for (int k4 = 0; k4 < K; k4 += 4) {
            float xk[RT][4];
            #pragma unroll
            for (int r = 0; r < RT; ++r) {
                float4 t = *(const float4*)&sX[(ty * RT + r) * K + k4];
                xk[r][0] = t.x; xk[r][1] = t.y; xk[r][2] = t.z; xk[r][3] = t.w;
            }
            float4 wv[4];
            #pragma unroll
            for (int kk = 0; kk < 4; ++kk)
                wv[kk] = *(const float4*)&sW[(k4 + kk) * F + tx * 4];
            #pragma unroll
            for (int kk = 0; kk < 4; ++kk)
                #pragma unroll
                for (int r = 0; r < RT; ++r) {
                    const float xr = xk[r][kk];
                    acc[r][0] = fmaf(xr, wv[kk].x, acc[r][0]);
                    acc[r][1] = fmaf(xr, wv[kk].y, acc[r][1]);
                    acc[r][2] = fmaf(xr, wv[kk].z, acc[r][2]);
                    acc[r][3] = fmaf(xr, wv[kk].w, acc[r][3]);
                }
        }

        #pragma unroll
        for (int r = 0; r < RT; ++r) {
            const int row = r0 + ty * RT + r;
            if (row < n) {
                if constexpr (EPI) {
                    float4 o;
                    o.x = fmaxf(acc[r][0] + bv.x, 0.f);
                    o.y = fmaxf(acc[r][1] + bv.y, 0.f);
                    o.z = fmaxf(acc[r][2] + bv.z, 0.f);
                    o.w = fmaxf(acc[r][3] + bv.w, 0.f);
                    ls[0] += o.x; lq[0] += o.x * o.x;
                    ls[1] += o.y; lq[1] += o.y * o.y;
                    ls[2] += o.z; lq[2] += o.z * o.z;
                    ls[3] += o.w; lq[3] += o.w * o.w;
                    *(float4*)&((float*)Ov)[(size_t)row * F + tx * 4] = o;
                } else {
                    union { float2 f2; __half2 h2[2]; } u;
                    u.h2[0] = __floats2half2_rn(acc[r][0], acc[r][1]);
                    u.h2[1] = __floats2half2_rn(acc[r][2], acc[r][3]);
                    *(float2*)&((__half*)Ov)[(size_t)row * F + tx * 4] = u.f2;
                }
            }
        }
    }

    if constexpr (EPI) {
        __syncthreads();
        if (tid < 2 * F) sRed[tid] = 0.f;
        __syncthreads();
        #pragma unroll
        for (int c = 0; c < 4; ++c) {
            atomicAdd(&sRed[tx * 4 + c], ls[c]);
            atomicAdd(&sRed[F + tx * 4 + c], lq[c]);
        }
        __syncthreads();
        if (tid < F) {
            atomicAdd(&sums[tid], sRed[tid]);
            atomicAdd(&sums[F + tid], sRed[F + tid]);
        }
    }
}

// ---------- half2 CSR gather aggregation, wave-per-node, 8-deep unroll ----------
template<int F>
__global__ __launch_bounds__(256) void k_aggh(const __half2* __restrict__ H2,
        const int* __restrict__ rs, const int* __restrict__ rend,
        const int* __restrict__ csrc, const float* __restrict__ dinv,
        const float* __restrict__ b, float* __restrict__ A,
        float* __restrict__ sums, int n) {
    constexpr int LPN = F / 2;           // lanes per node
    constexpr int NPW = 64 / LPN;        // nodes per wave
    __shared__ float sR[2 * F];
    const int tid = threadIdx.x;
    const int lane = tid & 63;
    const int wid = tid >> 6;
    const int sub = lane / LPN;
    const int fl = lane % LPN;
    const float2 bv = make_float2(b[2 * fl], b[2 * fl + 1]);
    const int gw = blockIdx.x * 4 + wid;
    const int nw = gridDim.x * 4;
    float ls0 = 0.f, lq0 = 0.f, ls1 = 0.f, lq1 = 0.f;

    for (int d = gw * NPW + sub; d < n; d += nw * NPW) {
        const int beg = rs[d], end = rend[d];
        const float di = dinv[d];
        float2 h = __half22float2(H2[(size_t)d * LPN + fl]);
        float ax = h.x * di, ay = h.y * di;     // self loop (x di again below)
        int j = beg;
        for (; j + 7 < end; j += 8) {
            int s[8];
            #pragma unroll
            for (int k = 0; k < 8; ++k) s[k] = csrc[j + k];
            float w[8]; __half2 hv[8];
            #pragma unroll
            for (int k = 0; k < 8; ++k) {
                w[k] = dinv[s[k]];
                hv[k] = H2[(size_t)s[k] * LPN + fl];
            }
            #pragma unroll
            for (int k = 0; k < 8; ++k) {
                float2 f = __half22float2(hv[k]);
                ax = fmaf(f.x, w[k], ax);
                ay = fmaf(f.y, w[k], ay);
            }
        }
        for (; j + 3 < end; j += 4) {
            int s[4];
            #pragma unroll
            for (int k = 0; k < 4; ++k) s[k] = csrc[j + k];
            float w[4]; __half2 hv[4];
            #pragma unroll
            for (int k = 0; k < 4; ++k) {
                w[k] = dinv[s[k]];
                hv[k] = H2[(size_t)s[k] * LPN + fl];
            }
            #pragma unroll
            for (int k = 0; k < 4; ++k) {
                float2 f = __half22float2(hv[k]);
                ax = fmaf(f.x, w[k], ax);
                ay = fmaf(f.y, w[k], ay);
            }
        }
        for (; j < end; ++j) {
            int s = csrc[j];
            float w = dinv[s];
            float2 f = __half22float2(H2[(size_t)s * LPN + fl]);
            ax = fmaf(f.x, w, ax);
            ay = fmaf(f.y, w, ay);
        }
        float vx = fmaxf(fmaf(ax, di, bv.x), 0.f);
        float vy = fmaxf(fmaf(ay, di, bv.y), 0.f);
        *(float2*)&A[(size_t)d * F + 2 * fl] = make_float2(vx, vy);
        ls0 += vx; lq0 += vx * vx;
        ls1 += vy; lq1 += vy * vy;
    }

    if (tid < 2 * F) sR[tid] = 0.f;
    __syncthreads();
    atomicAdd(&sR[2 * fl], ls0);
    atomicAdd(&sR[2 * fl + 1], ls1);
    atomicAdd(&sR[F + 2 * fl], lq0);
    atomicAdd(&sR[F + 2 * fl + 1], lq1);
    __syncthreads();
    if (tid < 2 * F) atomicAdd(&sums[tid], sR[tid]);
}

// ---------- BN fold ----------
__global__ void k_bnprep(const float* __restrict__ sums, const float* __restrict__ g,
                         const float* __restrict__ be, float* __restrict__ aff,
                         int F, float invn) {
    int f = threadIdx.x;
    if (f < F) {
        float mean = sums[f] * invn;
        float var = sums[F + f] * invn - mean * mean;
        float a = rsqrtf(var + BN_EPS) * g[f];
        aff[f] = a;
        aff[F + f] = be[f] - mean * a;
    }
}

// ---------- final 64->2 GEMM with input affine ----------
__global__ void k_gemm4(const float* __restrict__ X, const float* __restrict__ W,
                        const float* __restrict__ aff, float* __restrict__ H, int n) {
    int i = blockIdx.x * blockDim.x + threadIdx.x;
    if (i >= n) return;
    float a0 = 0.0f, a1 = 0.0f;
    #pragma unroll 8
    for (int k = 0; k < 64; ++k) {
        float v = X[i * 64 + k] * aff[k] + aff[64 + k];
        a0 = fmaf(v, W[2 * k], a0);
        a1 = fmaf(v, W[2 * k + 1], a1);
    }
    H[2 * i] = a0;
    H[2 * i + 1] = a1;
}

// ---------- final aggregation (F=2) + bias + log_softmax ----------
__global__ void k_last(const float* __restrict__ H, const int* __restrict__ rs,
                       const int* __restrict__ rend, const int* __restrict__ csrc,
                       const float* __restrict__ dinv, const float* __restrict__ b,
                       float* __restrict__ out, int n) {
    int d = blockIdx.x * blockDim.x + threadIdx.x;
    if (d >= n) return;
    const float di = dinv[d];
    float a0 = H[2 * d] * di, a1 = H[2 * d + 1] * di;
    const int beg = rs[d], end = rend[d];
    for (int j = beg; j < end; ++j) {
        int s = csrc[j];
        float w = dinv[s];
        a0 = fmaf(H[2 * s], w, a0);
        a1 = fmaf(H[2 * s + 1], w, a1);
    }
    float v0 = fmaf(a0, di, b[0]);
    float v1 = fmaf(a1, di, b[1]);
    float m = fmaxf(v0, v1);
    float l = logf(expf(v0 - m) + expf(v1 - m)) + m;
    out[2 * d] = v0 - l;
    out[2 * d + 1] = v1 - l;
}

extern "C" void kernel_launch(void* const* d_in, const int* in_sizes, int n_in,
                              void* d_out, int out_size, void* d_ws, size_t ws_size,
                              hipStream_t stream) {
    const float* x   = (const float*)d_in[0];
    const int*   ei  = (const int*)d_in[1];
    const float* W1  = (const float*)d_in[2];
    const float* b1  = (const float*)d_in[3];
    const float* g1  = (const float*)d_in[4];
    const float* be1 = (const float*)d_in[5];
    const float* W2  = (const float*)d_in[6];
    const float* b2  = (const float*)d_in[7];
    const float* g2  = (const float*)d_in[8];
    const float* be2 = (const float*)d_in[9];
    const float* W3  = (const float*)d_in[10];
    const float* b3  = (const float*)d_in[11];
    const float* g3  = (const float*)d_in[12];
    const float* be3 = (const float*)d_in[13];
    const float* W4  = (const float*)d_in[14];
    const float* b4  = (const float*)d_in[15];
    float* out = (float*)d_out;

    const int N = in_sizes[0] / 24;
    const int E = in_sizes[1] / 2;
    const int* srcI = ei;
    const int* dstI = ei + E;

    // ---- workspace carve ----
    int* cnt   = (int*)d_ws;                 // N
    int* rs    = cnt + N;                    // N
    int* cur   = rs + N;                     // N
    int* csrc  = cur + N;                    // E
    int* bsum  = csrc + E;                   // 1024
    float* dinv = (float*)(bsum + 1024);     // N
    float* Hbase = dinv + N;                 // N*128 f32 region (multi-use)
    float* A    = Hbase + (size_t)N * 128;   // N*128 f32
    float* S    = A + (size_t)N * 128;       // 1280 stats
    float* sums1 = S,        *aff1 = S + 256;
    float* sums2 = S + 512,  *aff2 = S + 768;
    float* sums3 = S + 1024, *aff3 = S + 1152;
    // aliases of Hbase (disjoint lifetimes, stream-ordered):
    float*  XA    = Hbase;                   // N*24 f32 (layer-1 pre-agg out)
    __half* Hh    = (__half*)Hbase;          // N*128 fp16 (layers 2/3)
    float*  LG    = Hbase;                   // N*2 logits (layer 4)
    // alias of A (dead until gemm1 writes it):
    __half* xh    = (__half*)A;              // N*24 fp16 copy of x

    hipMemsetAsync(S, 0, 1280 * sizeof(float), stream);

    const int TB = 256;
    const int nb1024 = (N + 1023) / 1024;

    // ---- CSR build + dinv ----
    k_zero_i<<<(N + TB - 1) / TB, TB, 0, stream>>>(cnt, N);
    k_count<<<(E + TB - 1) / TB, TB, 0, stream>>>(dstI, cnt, E);
    k_dinv<<<(N + TB - 1) / TB, TB, 0, stream>>>(cnt, dinv, N);
    k_scan1<<<nb1024, 1024, 0, stream>>>(cnt, rs, bsum, N);
    k_scan2<<<1, 1024, 0, stream>>>(bsum, nb1024);
    k_scan3<<<(N + TB - 1) / TB, TB, 0, stream>>>(rs, cur, bsum, N);
    k_fillx<<<256 * 8, TB, 0, stream>>>(srcI, dstI, cur, csrc, E, 256);
    // after k_fillx, cur[d] == row end

    // ----- layer 1: fp16 x, pre-aggregate (24-wide), GEMM 24->128 + epilogue -----
    k_x2h<<<(N * 24 / 4 + TB - 1) / TB, TB, 0, stream>>>(x, xh, N * 24 / 4);
    k_agg24h<<<2048, 256, 0, stream>>>(xh, rs, cur, csrc, dinv, XA, N);
    k_gemm2<24, 128, 4, false, true><<<1024, 256, 0, stream>>>(XA, W1, nullptr, A, b1, sums1, N);
    k_bnprep<<<1, 128, 0, stream>>>(sums1, g1, be1, aff1, 128, 1.0f / (float)N);

    // ----- layer 2: GEMM 128->128 (fp16 out), half2 gather agg -----
    k_gemm2<128, 128, 4, true, false><<<1024, 256, 0, stream>>>(A, W2, aff1, Hh, nullptr, nullptr, N);
    k_aggh<128><<<2048, 256, 0, stream>>>((const __half2*)Hh, rs, cur, csrc, dinv, b2, A, sums2, N);
    k_bnprep<<<1, 128, 0, stream>>>(sums2, g2, be2, aff2, 128, 1.0f / (float)N);

    // ----- layer 3: GEMM 128->64 (fp16 out), half2 gather agg -----
    k_gemm2<128, 64, 2, true, false><<<1024, 256, 0, stream>>>(A, W3, aff2, Hh, nullptr, nullptr, N);
    k_aggh<64><<<2048, 256, 0, stream>>>((const __half2*)Hh, rs, cur, csrc, dinv, b3, A, sums3, N);
    k_bnprep<<<1, 64, 0, stream>>>(sums3, g3, be3, aff3, 64, 1.0f / (float)N);

    // ----- layer 4: 64 -> 2, log_softmax -----
    k_gemm4<<<(N + TB - 1) / TB, TB, 0, stream>>>(A, W4, aff3, LG, N);
    k_last<<<(N + TB - 1) / TB, TB, 0, stream>>>(LG, rs, cur, csrc, dinv, b4, out, N);
}